// Round 1
// baseline (2105.550 us; speedup 1.0000x reference)
//
#include <hip/hip_runtime.h>

#define D 128

// ---- graph preprocessing ----------------------------------------------------

__global__ void k_degrees(const int* __restrict__ src, const int* __restrict__ dst,
                          int* __restrict__ outdeg, int* __restrict__ indeg, int E) {
  int i = blockIdx.x * blockDim.x + threadIdx.x;
  if (i < E) {
    atomicAdd(&outdeg[src[i]], 1);
    atomicAdd(&indeg[dst[i]], 1);
  }
}

__global__ void k_hist(const int* __restrict__ gid, int* __restrict__ h, int n) {
  int i = blockIdx.x * blockDim.x + threadIdx.x;
  if (i < n) atomicAdd(&h[gid[i]], 1);
}

__global__ void k_norms(const int* __restrict__ outdeg, const int* __restrict__ indeg,
                        float* __restrict__ ns, float* __restrict__ nd, int n) {
  int i = blockIdx.x * blockDim.x + threadIdx.x;
  if (i < n) {
    ns[i] = rsqrtf(fmaxf((float)outdeg[i], 1.f));
    nd[i] = rsqrtf(fmaxf((float)indeg[i], 1.f));
  }
}

// single-block exclusive scan; 256 threads, 1024 elems/iter
__global__ void k_exscan(const int* __restrict__ deg, int* __restrict__ rowptr, int n) {
  __shared__ int ssum[256];
  int t = threadIdx.x;
  int offset = 0;
  for (int base = 0; base < n; base += 1024) {
    int idx = base + t * 4;
    int a0 = (idx + 0 < n) ? deg[idx + 0] : 0;
    int a1 = (idx + 1 < n) ? deg[idx + 1] : 0;
    int a2 = (idx + 2 < n) ? deg[idx + 2] : 0;
    int a3 = (idx + 3 < n) ? deg[idx + 3] : 0;
    int s = a0 + a1 + a2 + a3;
    __syncthreads();
    ssum[t] = s;
    __syncthreads();
    for (int d = 1; d < 256; d <<= 1) {
      int val = (t >= d) ? ssum[t - d] : 0;
      __syncthreads();
      ssum[t] += val;
      __syncthreads();
    }
    int o = offset + ssum[t] - s;
    if (idx + 0 < n) rowptr[idx + 0] = o; o += a0;
    if (idx + 1 < n) rowptr[idx + 1] = o; o += a1;
    if (idx + 2 < n) rowptr[idx + 2] = o; o += a2;
    if (idx + 3 < n) rowptr[idx + 3] = o;
    offset += ssum[255];
  }
  if (t == 0) rowptr[n] = offset;
}

__global__ void k_build_col(const int* __restrict__ src, const int* __restrict__ dst,
                            const int* __restrict__ rowptr, int* __restrict__ cnt,
                            int* __restrict__ col, int E) {
  int i = blockIdx.x * blockDim.x + threadIdx.x;
  if (i < E) {
    int d = dst[i];
    int pos = rowptr[d] + atomicAdd(&cnt[d], 1);
    col[pos] = src[i];
  }
}

__global__ void k_build_list(const int* __restrict__ gid, const int* __restrict__ rowptr,
                             int* __restrict__ cnt, int* __restrict__ list, int n) {
  int i = blockIdx.x * blockDim.x + threadIdx.x;
  if (i < n) {
    int g = gid[i];
    int pos = rowptr[g] + atomicAdd(&cnt[g], 1);
    list[pos] = i;
  }
}

// ---- GraphConv pieces -------------------------------------------------------

// h[v] = (x[v] * ns[v]) @ W   — one block (128 threads) per node
__global__ void k_node_linear(const float* __restrict__ x, const float* __restrict__ ns,
                              const float* __restrict__ W, float* __restrict__ h, int K) {
  __shared__ float xs[128];
  int v = blockIdx.x, t = threadIdx.x;
  if (t < K) xs[t] = x[(size_t)v * K + t] * ns[v];
  __syncthreads();
  float acc = 0.f;
  for (int k = 0; k < K; ++k) acc = fmaf(xs[k], W[k * D + t], acc);
  h[(size_t)v * D + t] = acc;
}

// out[v] = relu( (sum_{e: dst==v} h[src_e]) * nd[v] + b ) — gather CSR, block per node
__global__ void k_aggregate(const float* __restrict__ h, const int* __restrict__ rowptr,
                            const int* __restrict__ col, const float* __restrict__ nd,
                            const float* __restrict__ b, float* __restrict__ out) {
  int v = blockIdx.x, t = threadIdx.x;
  int beg = rowptr[v], end = rowptr[v + 1];
  float acc = 0.f;
  for (int j = beg; j < end; ++j) {
    int s = col[j];
    acc += h[(size_t)s * D + t];
  }
  out[(size_t)v * D + t] = fmaxf(fmaf(acc, nd[v], b[t]), 0.f);
}

// mean over nodes of each graph — atomic-free via gid-CSR
__global__ void k_seg_mean(const float* __restrict__ x, const int* __restrict__ rowptr,
                           const int* __restrict__ list, float* __restrict__ out) {
  int g = blockIdx.x, t = threadIdx.x;
  int beg = rowptr[g], end = rowptr[g + 1];
  float acc = 0.f;
  for (int j = beg; j < end; ++j) acc += x[(size_t)list[j] * D + t];
  out[g * D + t] = acc / fmaxf((float)(end - beg), 1.f);
}

// fused predictor: relu([cg,pg]@Wf1 + bf1) @ Wf2 + bf2 — one block per graph
__global__ void k_mlp(const float* __restrict__ cg, const float* __restrict__ pg,
                      const float* __restrict__ Wf1, const float* __restrict__ bf1,
                      const float* __restrict__ Wf2, const float* __restrict__ bf2,
                      float* __restrict__ out) {
  __shared__ float xs[256];
  __shared__ float red[128];
  int b = blockIdx.x, t = threadIdx.x;
  xs[t] = cg[b * D + t];
  xs[128 + t] = pg[b * D + t];
  __syncthreads();
  float acc = bf1[t];
  for (int k = 0; k < 256; ++k) acc = fmaf(xs[k], Wf1[k * D + t], acc);
  float hv = fmaxf(acc, 0.f);
  red[t] = hv * Wf2[t];
  for (int d = 64; d > 0; d >>= 1) {
    __syncthreads();
    if (t < d) red[t] += red[t + d];
  }
  if (t == 0) out[b] = red[0] + bf2[0];
}

// ---- launch -----------------------------------------------------------------

extern "C" void kernel_launch(void* const* d_in, const int* in_sizes, int n_in,
                              void* d_out, int out_size, void* d_ws, size_t ws_size,
                              hipStream_t stream) {
  const float* compound_feat = (const float*)d_in[0];
  const float* protein_feat  = (const float*)d_in[1];
  const int* c_src = (const int*)d_in[2];
  const int* c_dst = (const int*)d_in[3];
  const int* p_src = (const int*)d_in[4];
  const int* p_dst = (const int*)d_in[5];
  const int* c_gid = (const int*)d_in[6];
  const int* p_gid = (const int*)d_in[7];
  const float* Wc1 = (const float*)d_in[8];  const float* bc1 = (const float*)d_in[9];
  const float* Wc2 = (const float*)d_in[10]; const float* bc2 = (const float*)d_in[11];
  const float* Wp1 = (const float*)d_in[12]; const float* bp1 = (const float*)d_in[13];
  const float* Wp2 = (const float*)d_in[14]; const float* bp2 = (const float*)d_in[15];
  const float* Wf1 = (const float*)d_in[16]; const float* bf1 = (const float*)d_in[17];
  const float* Wf2 = (const float*)d_in[18]; const float* bf2 = (const float*)d_in[19];
  float* out = (float*)d_out;

  const int EC = in_sizes[2], EP = in_sizes[4];
  const int NC = in_sizes[6], NP = in_sizes[7];
  const int B  = out_size;                 // 256
  const int KC = in_sizes[0] / NC;         // 74

  char* ws = (char*)d_ws;
  size_t off = 0;
  auto alloc = [&](size_t bytes) -> void* {
    void* p = ws + off;
    off += (bytes + 255) & ~(size_t)255;
    return p;
  };

  // --- zero-init block (kept contiguous so one memset covers it) ---
  int* c_outdeg = (int*)alloc((size_t)NC * 4);
  int* c_indeg  = (int*)alloc((size_t)NC * 4);
  int* c_cnt    = (int*)alloc((size_t)NC * 4);
  int* p_outdeg = (int*)alloc((size_t)NP * 4);
  int* p_indeg  = (int*)alloc((size_t)NP * 4);
  int* p_cnt    = (int*)alloc((size_t)NP * 4);
  int* cg_hist  = (int*)alloc((size_t)B * 4);
  int* cg_cnt   = (int*)alloc((size_t)B * 4);
  int* pg_hist  = (int*)alloc((size_t)B * 4);
  int* pg_cnt   = (int*)alloc((size_t)B * 4);
  size_t zero_bytes = off;

  float* c_ns = (float*)alloc((size_t)NC * 4);
  float* c_nd = (float*)alloc((size_t)NC * 4);
  float* p_ns = (float*)alloc((size_t)NP * 4);
  float* p_nd = (float*)alloc((size_t)NP * 4);
  int* c_rowptr  = (int*)alloc((size_t)(NC + 1) * 4);
  int* p_rowptr  = (int*)alloc((size_t)(NP + 1) * 4);
  int* cg_rowptr = (int*)alloc((size_t)(B + 1) * 4);
  int* pg_rowptr = (int*)alloc((size_t)(B + 1) * 4);
  int* c_col   = (int*)alloc((size_t)EC * 4);
  int* p_col   = (int*)alloc((size_t)EP * 4);
  int* cg_list = (int*)alloc((size_t)NC * 4);
  int* pg_list = (int*)alloc((size_t)NP * 4);
  float* c_h = (float*)alloc((size_t)NC * D * 4);
  float* c_m = (float*)alloc((size_t)NC * D * 4);
  float* p_h = (float*)alloc((size_t)NP * D * 4);
  float* p_m = (float*)alloc((size_t)NP * D * 4);
  float* cg = (float*)alloc((size_t)B * D * 4);
  float* pg = (float*)alloc((size_t)B * D * 4);
  (void)ws_size; (void)n_in;

  hipMemsetAsync((void*)c_outdeg, 0, zero_bytes, stream);

  const int tb = 256;
  k_degrees<<<(EC + tb - 1) / tb, tb, 0, stream>>>(c_src, c_dst, c_outdeg, c_indeg, EC);
  k_degrees<<<(EP + tb - 1) / tb, tb, 0, stream>>>(p_src, p_dst, p_outdeg, p_indeg, EP);
  k_hist<<<(NC + tb - 1) / tb, tb, 0, stream>>>(c_gid, cg_hist, NC);
  k_hist<<<(NP + tb - 1) / tb, tb, 0, stream>>>(p_gid, pg_hist, NP);
  k_norms<<<(NC + tb - 1) / tb, tb, 0, stream>>>(c_outdeg, c_indeg, c_ns, c_nd, NC);
  k_norms<<<(NP + tb - 1) / tb, tb, 0, stream>>>(p_outdeg, p_indeg, p_ns, p_nd, NP);
  k_exscan<<<1, 256, 0, stream>>>(c_indeg, c_rowptr, NC);
  k_exscan<<<1, 256, 0, stream>>>(p_indeg, p_rowptr, NP);
  k_exscan<<<1, 256, 0, stream>>>(cg_hist, cg_rowptr, B);
  k_exscan<<<1, 256, 0, stream>>>(pg_hist, pg_rowptr, B);
  k_build_col<<<(EC + tb - 1) / tb, tb, 0, stream>>>(c_src, c_dst, c_rowptr, c_cnt, c_col, EC);
  k_build_col<<<(EP + tb - 1) / tb, tb, 0, stream>>>(p_src, p_dst, p_rowptr, p_cnt, p_col, EP);
  k_build_list<<<(NC + tb - 1) / tb, tb, 0, stream>>>(c_gid, cg_rowptr, cg_cnt, cg_list, NC);
  k_build_list<<<(NP + tb - 1) / tb, tb, 0, stream>>>(p_gid, pg_rowptr, pg_cnt, pg_list, NP);

  // compound tower
  k_node_linear<<<NC, D, 0, stream>>>(compound_feat, c_ns, Wc1, c_h, KC);
  k_aggregate<<<NC, D, 0, stream>>>(c_h, c_rowptr, c_col, c_nd, bc1, c_m);
  k_node_linear<<<NC, D, 0, stream>>>(c_m, c_ns, Wc2, c_h, D);
  k_aggregate<<<NC, D, 0, stream>>>(c_h, c_rowptr, c_col, c_nd, bc2, c_m);
  k_seg_mean<<<B, D, 0, stream>>>(c_m, cg_rowptr, cg_list, cg);

  // protein tower
  k_node_linear<<<NP, D, 0, stream>>>(protein_feat, p_ns, Wp1, p_h, D);
  k_aggregate<<<NP, D, 0, stream>>>(p_h, p_rowptr, p_col, p_nd, bp1, p_m);
  k_node_linear<<<NP, D, 0, stream>>>(p_m, p_ns, Wp2, p_h, D);
  k_aggregate<<<NP, D, 0, stream>>>(p_h, p_rowptr, p_col, p_nd, bp2, p_m);
  k_seg_mean<<<B, D, 0, stream>>>(p_m, pg_rowptr, pg_list, pg);

  k_mlp<<<B, D, 0, stream>>>(cg, pg, Wf1, bf1, Wf2, bf2, out);
}

// Round 2
// 1516.530 us; speedup vs baseline: 1.3884x; 1.3884x over previous
//
#include <hip/hip_runtime.h>

#define D 128
#define KP 132      // padded LDS row stride for x tile (breaks bank conflicts, keeps 16B align)
#define SCH 4096    // elements per scan block

// ---- graph preprocessing ----------------------------------------------------

__global__ void k_degrees(const int* __restrict__ src, const int* __restrict__ dst,
                          int* __restrict__ outdeg, int* __restrict__ indeg, int E) {
  int i = blockIdx.x * blockDim.x + threadIdx.x;
  if (i < E) {
    atomicAdd(&outdeg[src[i]], 1);
    atomicAdd(&indeg[dst[i]], 1);
  }
}

__global__ void k_hist(const int* __restrict__ gid, int* __restrict__ h, int n) {
  int i = blockIdx.x * blockDim.x + threadIdx.x;
  if (i < n) atomicAdd(&h[gid[i]], 1);
}

__global__ void k_norms(const int* __restrict__ outdeg, const int* __restrict__ indeg,
                        float* __restrict__ ns, float* __restrict__ nd, int n) {
  int i = blockIdx.x * blockDim.x + threadIdx.x;
  if (i < n) {
    ns[i] = rsqrtf(fmaxf((float)outdeg[i], 1.f));
    nd[i] = rsqrtf(fmaxf((float)indeg[i], 1.f));
  }
}

// ---- hierarchical exclusive scan (3 phases) ---------------------------------

__global__ void k_scan_part(const int* __restrict__ deg, int* __restrict__ part, int n) {
  int b = blockIdx.x, t = threadIdx.x;
  int base = b * SCH;
  int s = 0;
  for (int i = t; i < SCH; i += 256) {
    int idx = base + i;
    if (idx < n) s += deg[idx];
  }
  __shared__ int red[256];
  red[t] = s;
  __syncthreads();
  for (int d = 128; d > 0; d >>= 1) {
    if (t < d) red[t] += red[t + d];
    __syncthreads();
  }
  if (t == 0) part[b] = red[0];
}

// exclusive-scan the (<=64) partials serially; also write rowptr[n] = total
__global__ void k_scan_top(int* __restrict__ part, int nb, int* __restrict__ rowptr, int n) {
  if (threadIdx.x == 0) {
    int run = 0;
    for (int i = 0; i < nb; ++i) { int v = part[i]; part[i] = run; run += v; }
    rowptr[n] = run;
  }
}

__global__ void k_scan_down(const int* __restrict__ deg, const int* __restrict__ part,
                            int* __restrict__ rowptr, int n) {
  int b = blockIdx.x, t = threadIdx.x;
  int lane = t & 63, wid = t >> 6;
  __shared__ int wsum[4];
  int base = b * SCH;
  int offset = part[b];
  int idx0 = base + t * 16;
  int v[16];
  int s = 0;
#pragma unroll
  for (int i = 0; i < 16; ++i) {
    int idx = idx0 + i;
    v[i] = (idx < n) ? deg[idx] : 0;
    s += v[i];
  }
  int inc = s;
  for (int d = 1; d < 64; d <<= 1) {
    int u = __shfl_up(inc, d, 64);
    if (lane >= d) inc += u;
  }
  if (lane == 63) wsum[wid] = inc;
  __syncthreads();
  int woff = 0;
  for (int w = 0; w < wid; ++w) woff += wsum[w];
  int ex = offset + woff + inc - s;
#pragma unroll
  for (int i = 0; i < 16; ++i) {
    int idx = idx0 + i;
    if (idx < n) rowptr[idx] = ex;
    ex += v[i];
  }
}

__global__ void k_build_col(const int* __restrict__ src, const int* __restrict__ dst,
                            const int* __restrict__ rowptr, int* __restrict__ cnt,
                            int* __restrict__ col, int E) {
  int i = blockIdx.x * blockDim.x + threadIdx.x;
  if (i < E) {
    int d = dst[i];
    int pos = rowptr[d] + atomicAdd(&cnt[d], 1);
    col[pos] = src[i];
  }
}

__global__ void k_build_list(const int* __restrict__ gid, const int* __restrict__ rowptr,
                             int* __restrict__ cnt, int* __restrict__ list, int n) {
  int i = blockIdx.x * blockDim.x + threadIdx.x;
  if (i < n) {
    int g = gid[i];
    int pos = rowptr[g] + atomicAdd(&cnt[g], 1);
    list[pos] = i;
  }
}

// ---- node-feature GEMM: h[v,:] = ns[v] * (x[v,:] @ W) -----------------------
// Tile: 32 nodes x 128 features per 256-thread block; thread computes 4x4.
// 16 FMAs per (1 ds_read_b128 + 1 global float4) -> FMA-bound.
__global__ __launch_bounds__(256) void k_nl_gemm(const float* __restrict__ x,
                                                 const float* __restrict__ ns,
                                                 const float* __restrict__ W,
                                                 float* __restrict__ h, int K) {
  __shared__ float xs[32][KP];
  int t = threadIdx.x;
  int v0 = blockIdx.x * 32;

  // stage x tile (coalesced: 32 consecutive k per lane-group, 8 rows per pass)
  {
    int m = t >> 5, k = t & 31;
    for (int kk = k; kk < K; kk += 32)
      for (int mm = m; mm < 32; mm += 8)
        xs[mm][kk] = x[(size_t)(v0 + mm) * K + kk];
  }
  __syncthreads();

  int tm = (t >> 5) * 4;       // node sub-tile base (0..28)
  int tf = (t & 31) * 4;       // feature sub-tile base (0..124)

  float acc[4][4];
#pragma unroll
  for (int i = 0; i < 4; ++i)
#pragma unroll
    for (int j = 0; j < 4; ++j) acc[i][j] = 0.f;

  int k4max = K & ~3;
  for (int k4 = 0; k4 < k4max; k4 += 4) {
    float a[4][4], bb[4][4];
#pragma unroll
    for (int kk = 0; kk < 4; ++kk) {
      float4 w4 = *(const float4*)&W[(k4 + kk) * D + tf];
      bb[kk][0] = w4.x; bb[kk][1] = w4.y; bb[kk][2] = w4.z; bb[kk][3] = w4.w;
    }
#pragma unroll
    for (int i = 0; i < 4; ++i) {
      float4 a4 = *(const float4*)&xs[tm + i][k4];
      a[i][0] = a4.x; a[i][1] = a4.y; a[i][2] = a4.z; a[i][3] = a4.w;
    }
#pragma unroll
    for (int i = 0; i < 4; ++i)
#pragma unroll
      for (int kk = 0; kk < 4; ++kk)
#pragma unroll
        for (int j = 0; j < 4; ++j)
          acc[i][j] = fmaf(a[i][kk], bb[kk][j], acc[i][j]);
  }
  // K tail (e.g. K=74)
  for (int k = k4max; k < K; ++k) {
    float4 w4 = *(const float4*)&W[k * D + tf];
    float bv[4] = {w4.x, w4.y, w4.z, w4.w};
#pragma unroll
    for (int i = 0; i < 4; ++i) {
      float av = xs[tm + i][k];
#pragma unroll
      for (int j = 0; j < 4; ++j) acc[i][j] = fmaf(av, bv[j], acc[i][j]);
    }
  }

#pragma unroll
  for (int i = 0; i < 4; ++i) {
    int v = v0 + tm + i;
    float s = ns[v];
    float4 o;
    o.x = acc[i][0] * s; o.y = acc[i][1] * s; o.z = acc[i][2] * s; o.w = acc[i][3] * s;
    *(float4*)&h[(size_t)v * D + tf] = o;
  }
}

// ---- aggregation / pooling / MLP --------------------------------------------

// out[v] = relu( (sum_{e: dst==v} h[src_e]) * nd[v] + b ) — gather CSR, block per node
__global__ void k_aggregate(const float* __restrict__ h, const int* __restrict__ rowptr,
                            const int* __restrict__ col, const float* __restrict__ nd,
                            const float* __restrict__ b, float* __restrict__ out) {
  int v = blockIdx.x, t = threadIdx.x;
  int beg = rowptr[v], end = rowptr[v + 1];
  float acc = 0.f;
  for (int j = beg; j < end; ++j) {
    int s = col[j];
    acc += h[(size_t)s * D + t];
  }
  out[(size_t)v * D + t] = fmaxf(fmaf(acc, nd[v], b[t]), 0.f);
}

__global__ void k_seg_mean(const float* __restrict__ x, const int* __restrict__ rowptr,
                           const int* __restrict__ list, float* __restrict__ out) {
  int g = blockIdx.x, t = threadIdx.x;
  int beg = rowptr[g], end = rowptr[g + 1];
  float acc = 0.f;
  for (int j = beg; j < end; ++j) acc += x[(size_t)list[j] * D + t];
  out[g * D + t] = acc / fmaxf((float)(end - beg), 1.f);
}

__global__ void k_mlp(const float* __restrict__ cg, const float* __restrict__ pg,
                      const float* __restrict__ Wf1, const float* __restrict__ bf1,
                      const float* __restrict__ Wf2, const float* __restrict__ bf2,
                      float* __restrict__ out) {
  __shared__ float xs[256];
  __shared__ float red[128];
  int b = blockIdx.x, t = threadIdx.x;
  xs[t] = cg[b * D + t];
  xs[128 + t] = pg[b * D + t];
  __syncthreads();
  float acc = bf1[t];
  for (int k = 0; k < 256; ++k) acc = fmaf(xs[k], Wf1[k * D + t], acc);
  float hv = fmaxf(acc, 0.f);
  red[t] = hv * Wf2[t];
  for (int d = 64; d > 0; d >>= 1) {
    __syncthreads();
    if (t < d) red[t] += red[t + d];
  }
  if (t == 0) out[b] = red[0] + bf2[0];
}

// ---- launch -----------------------------------------------------------------

extern "C" void kernel_launch(void* const* d_in, const int* in_sizes, int n_in,
                              void* d_out, int out_size, void* d_ws, size_t ws_size,
                              hipStream_t stream) {
  const float* compound_feat = (const float*)d_in[0];
  const float* protein_feat  = (const float*)d_in[1];
  const int* c_src = (const int*)d_in[2];
  const int* c_dst = (const int*)d_in[3];
  const int* p_src = (const int*)d_in[4];
  const int* p_dst = (const int*)d_in[5];
  const int* c_gid = (const int*)d_in[6];
  const int* p_gid = (const int*)d_in[7];
  const float* Wc1 = (const float*)d_in[8];  const float* bc1 = (const float*)d_in[9];
  const float* Wc2 = (const float*)d_in[10]; const float* bc2 = (const float*)d_in[11];
  const float* Wp1 = (const float*)d_in[12]; const float* bp1 = (const float*)d_in[13];
  const float* Wp2 = (const float*)d_in[14]; const float* bp2 = (const float*)d_in[15];
  const float* Wf1 = (const float*)d_in[16]; const float* bf1 = (const float*)d_in[17];
  const float* Wf2 = (const float*)d_in[18]; const float* bf2 = (const float*)d_in[19];
  float* out = (float*)d_out;

  const int EC = in_sizes[2], EP = in_sizes[4];
  const int NC = in_sizes[6], NP = in_sizes[7];
  const int B  = out_size;                 // 256
  const int KC = in_sizes[0] / NC;         // 74

  char* ws = (char*)d_ws;
  size_t off = 0;
  auto alloc = [&](size_t bytes) -> void* {
    void* p = ws + off;
    off += (bytes + 255) & ~(size_t)255;
    return p;
  };

  // --- zero-init block (kept contiguous so one memset covers it) ---
  int* c_outdeg = (int*)alloc((size_t)NC * 4);
  int* c_indeg  = (int*)alloc((size_t)NC * 4);
  int* c_cnt    = (int*)alloc((size_t)NC * 4);
  int* p_outdeg = (int*)alloc((size_t)NP * 4);
  int* p_indeg  = (int*)alloc((size_t)NP * 4);
  int* p_cnt    = (int*)alloc((size_t)NP * 4);
  int* cg_hist  = (int*)alloc((size_t)B * 4);
  int* cg_cnt   = (int*)alloc((size_t)B * 4);
  int* pg_hist  = (int*)alloc((size_t)B * 4);
  int* pg_cnt   = (int*)alloc((size_t)B * 4);
  size_t zero_bytes = off;

  float* c_ns = (float*)alloc((size_t)NC * 4);
  float* c_nd = (float*)alloc((size_t)NC * 4);
  float* p_ns = (float*)alloc((size_t)NP * 4);
  float* p_nd = (float*)alloc((size_t)NP * 4);
  int* c_rowptr  = (int*)alloc((size_t)(NC + 1) * 4);
  int* p_rowptr  = (int*)alloc((size_t)(NP + 1) * 4);
  int* cg_rowptr = (int*)alloc((size_t)(B + 1) * 4);
  int* pg_rowptr = (int*)alloc((size_t)(B + 1) * 4);
  int* c_part  = (int*)alloc(64 * 4);
  int* p_part  = (int*)alloc(64 * 4);
  int* cg_part = (int*)alloc(64 * 4);
  int* pg_part = (int*)alloc(64 * 4);
  int* c_col   = (int*)alloc((size_t)EC * 4);
  int* p_col   = (int*)alloc((size_t)EP * 4);
  int* cg_list = (int*)alloc((size_t)NC * 4);
  int* pg_list = (int*)alloc((size_t)NP * 4);
  float* c_h = (float*)alloc((size_t)NC * D * 4);
  float* c_m = (float*)alloc((size_t)NC * D * 4);
  float* p_h = (float*)alloc((size_t)NP * D * 4);
  float* p_m = (float*)alloc((size_t)NP * D * 4);
  float* cg = (float*)alloc((size_t)B * D * 4);
  float* pg = (float*)alloc((size_t)B * D * 4);
  (void)ws_size; (void)n_in;

  hipMemsetAsync((void*)c_outdeg, 0, zero_bytes, stream);

  const int tb = 256;
  k_degrees<<<(EC + tb - 1) / tb, tb, 0, stream>>>(c_src, c_dst, c_outdeg, c_indeg, EC);
  k_degrees<<<(EP + tb - 1) / tb, tb, 0, stream>>>(p_src, p_dst, p_outdeg, p_indeg, EP);
  k_hist<<<(NC + tb - 1) / tb, tb, 0, stream>>>(c_gid, cg_hist, NC);
  k_hist<<<(NP + tb - 1) / tb, tb, 0, stream>>>(p_gid, pg_hist, NP);
  k_norms<<<(NC + tb - 1) / tb, tb, 0, stream>>>(c_outdeg, c_indeg, c_ns, c_nd, NC);
  k_norms<<<(NP + tb - 1) / tb, tb, 0, stream>>>(p_outdeg, p_indeg, p_ns, p_nd, NP);

  // hierarchical exclusive scans
  {
    int nbc = (NC + SCH - 1) / SCH, nbp = (NP + SCH - 1) / SCH, nbb = (B + SCH - 1) / SCH;
    k_scan_part<<<nbc, 256, 0, stream>>>(c_indeg, c_part, NC);
    k_scan_part<<<nbp, 256, 0, stream>>>(p_indeg, p_part, NP);
    k_scan_part<<<nbb, 256, 0, stream>>>(cg_hist, cg_part, B);
    k_scan_part<<<nbb, 256, 0, stream>>>(pg_hist, pg_part, B);
    k_scan_top<<<1, 64, 0, stream>>>(c_part, nbc, c_rowptr, NC);
    k_scan_top<<<1, 64, 0, stream>>>(p_part, nbp, p_rowptr, NP);
    k_scan_top<<<1, 64, 0, stream>>>(cg_part, nbb, cg_rowptr, B);
    k_scan_top<<<1, 64, 0, stream>>>(pg_part, nbb, pg_rowptr, B);
    k_scan_down<<<nbc, 256, 0, stream>>>(c_indeg, c_part, c_rowptr, NC);
    k_scan_down<<<nbp, 256, 0, stream>>>(p_indeg, p_part, p_rowptr, NP);
    k_scan_down<<<nbb, 256, 0, stream>>>(cg_hist, cg_part, cg_rowptr, B);
    k_scan_down<<<nbb, 256, 0, stream>>>(pg_hist, pg_part, pg_rowptr, B);
  }

  k_build_col<<<(EC + tb - 1) / tb, tb, 0, stream>>>(c_src, c_dst, c_rowptr, c_cnt, c_col, EC);
  k_build_col<<<(EP + tb - 1) / tb, tb, 0, stream>>>(p_src, p_dst, p_rowptr, p_cnt, p_col, EP);
  k_build_list<<<(NC + tb - 1) / tb, tb, 0, stream>>>(c_gid, cg_rowptr, cg_cnt, cg_list, NC);
  k_build_list<<<(NP + tb - 1) / tb, tb, 0, stream>>>(p_gid, pg_rowptr, pg_cnt, pg_list, NP);

  // compound tower
  k_nl_gemm<<<NC / 32, 256, 0, stream>>>(compound_feat, c_ns, Wc1, c_h, KC);
  k_aggregate<<<NC, D, 0, stream>>>(c_h, c_rowptr, c_col, c_nd, bc1, c_m);
  k_nl_gemm<<<NC / 32, 256, 0, stream>>>(c_m, c_ns, Wc2, c_h, D);
  k_aggregate<<<NC, D, 0, stream>>>(c_h, c_rowptr, c_col, c_nd, bc2, c_m);
  k_seg_mean<<<B, D, 0, stream>>>(c_m, cg_rowptr, cg_list, cg);

  // protein tower
  k_nl_gemm<<<NP / 32, 256, 0, stream>>>(protein_feat, p_ns, Wp1, p_h, D);
  k_aggregate<<<NP, D, 0, stream>>>(p_h, p_rowptr, p_col, p_nd, bp1, p_m);
  k_nl_gemm<<<NP / 32, 256, 0, stream>>>(p_m, p_ns, Wp2, p_h, D);
  k_aggregate<<<NP, D, 0, stream>>>(p_h, p_rowptr, p_col, p_nd, bp2, p_m);
  k_seg_mean<<<B, D, 0, stream>>>(p_m, pg_rowptr, pg_list, pg);

  k_mlp<<<B, D, 0, stream>>>(cg, pg, Wf1, bf1, Wf2, bf2, out);
}

// Round 3
// 1199.911 us; speedup vs baseline: 1.7548x; 1.2639x over previous
//
#include <hip/hip_runtime.h>

#define D 128
#define KP 132      // padded LDS row stride for x tile (breaks bank conflicts, keeps 16B align)
#define SCH 4096    // elements per scan block

// ---- graph preprocessing ----------------------------------------------------

__global__ void k_degrees(const int* __restrict__ src, const int* __restrict__ dst,
                          int* __restrict__ outdeg, int* __restrict__ indeg, int E) {
  int i = blockIdx.x * blockDim.x + threadIdx.x;
  if (i < E) {
    atomicAdd(&outdeg[src[i]], 1);
    atomicAdd(&indeg[dst[i]], 1);
  }
}

__global__ void k_hist(const int* __restrict__ gid, int* __restrict__ h, int n) {
  int i = blockIdx.x * blockDim.x + threadIdx.x;
  if (i < n) atomicAdd(&h[gid[i]], 1);
}

__global__ void k_norms(const int* __restrict__ outdeg, const int* __restrict__ indeg,
                        float* __restrict__ ns, float* __restrict__ nd, int n) {
  int i = blockIdx.x * blockDim.x + threadIdx.x;
  if (i < n) {
    ns[i] = rsqrtf(fmaxf((float)outdeg[i], 1.f));
    nd[i] = rsqrtf(fmaxf((float)indeg[i], 1.f));
  }
}

// ---- hierarchical exclusive scan (3 phases) ---------------------------------

__global__ void k_scan_part(const int* __restrict__ deg, int* __restrict__ part, int n) {
  int b = blockIdx.x, t = threadIdx.x;
  int base = b * SCH;
  int s = 0;
  for (int i = t; i < SCH; i += 256) {
    int idx = base + i;
    if (idx < n) s += deg[idx];
  }
  __shared__ int red[256];
  red[t] = s;
  __syncthreads();
  for (int d = 128; d > 0; d >>= 1) {
    if (t < d) red[t] += red[t + d];
    __syncthreads();
  }
  if (t == 0) part[b] = red[0];
}

__global__ void k_scan_top(int* __restrict__ part, int nb, int* __restrict__ rowptr, int n) {
  if (threadIdx.x == 0) {
    int run = 0;
    for (int i = 0; i < nb; ++i) { int v = part[i]; part[i] = run; run += v; }
    rowptr[n] = run;
  }
}

__global__ void k_scan_down(const int* __restrict__ deg, const int* __restrict__ part,
                            int* __restrict__ rowptr, int n) {
  int b = blockIdx.x, t = threadIdx.x;
  int lane = t & 63, wid = t >> 6;
  __shared__ int wsum[4];
  int base = b * SCH;
  int offset = part[b];
  int idx0 = base + t * 16;
  int v[16];
  int s = 0;
#pragma unroll
  for (int i = 0; i < 16; ++i) {
    int idx = idx0 + i;
    v[i] = (idx < n) ? deg[idx] : 0;
    s += v[i];
  }
  int inc = s;
  for (int d = 1; d < 64; d <<= 1) {
    int u = __shfl_up(inc, d, 64);
    if (lane >= d) inc += u;
  }
  if (lane == 63) wsum[wid] = inc;
  __syncthreads();
  int woff = 0;
  for (int w = 0; w < wid; ++w) woff += wsum[w];
  int ex = offset + woff + inc - s;
#pragma unroll
  for (int i = 0; i < 16; ++i) {
    int idx = idx0 + i;
    if (idx < n) rowptr[idx] = ex;
    ex += v[i];
  }
}

__global__ void k_build_col(const int* __restrict__ src, const int* __restrict__ dst,
                            const int* __restrict__ rowptr, int* __restrict__ cnt,
                            int* __restrict__ col, int E) {
  int i = blockIdx.x * blockDim.x + threadIdx.x;
  if (i < E) {
    int d = dst[i];
    int pos = rowptr[d] + atomicAdd(&cnt[d], 1);
    col[pos] = src[i];
  }
}

__global__ void k_build_list(const int* __restrict__ gid, const int* __restrict__ rowptr,
                             int* __restrict__ cnt, int* __restrict__ list, int n) {
  int i = blockIdx.x * blockDim.x + threadIdx.x;
  if (i < n) {
    int g = gid[i];
    int pos = rowptr[g] + atomicAdd(&cnt[g], 1);
    list[pos] = i;
  }
}

// ---- node-feature GEMM: h[v,:] = ns[v] * (x[v,:] @ W) -----------------------
__global__ __launch_bounds__(256) void k_nl_gemm(const float* __restrict__ x,
                                                 const float* __restrict__ ns,
                                                 const float* __restrict__ W,
                                                 float* __restrict__ h, int K) {
  __shared__ float xs[32][KP];
  int t = threadIdx.x;
  int v0 = blockIdx.x * 32;

  {
    int m = t >> 5, k = t & 31;
    for (int kk = k; kk < K; kk += 32)
      for (int mm = m; mm < 32; mm += 8)
        xs[mm][kk] = x[(size_t)(v0 + mm) * K + kk];
  }
  __syncthreads();

  int tm = (t >> 5) * 4;
  int tf = (t & 31) * 4;

  float acc[4][4];
#pragma unroll
  for (int i = 0; i < 4; ++i)
#pragma unroll
    for (int j = 0; j < 4; ++j) acc[i][j] = 0.f;

  int k4max = K & ~3;
  for (int k4 = 0; k4 < k4max; k4 += 4) {
    float a[4][4], bb[4][4];
#pragma unroll
    for (int kk = 0; kk < 4; ++kk) {
      float4 w4 = *(const float4*)&W[(k4 + kk) * D + tf];
      bb[kk][0] = w4.x; bb[kk][1] = w4.y; bb[kk][2] = w4.z; bb[kk][3] = w4.w;
    }
#pragma unroll
    for (int i = 0; i < 4; ++i) {
      float4 a4 = *(const float4*)&xs[tm + i][k4];
      a[i][0] = a4.x; a[i][1] = a4.y; a[i][2] = a4.z; a[i][3] = a4.w;
    }
#pragma unroll
    for (int i = 0; i < 4; ++i)
#pragma unroll
      for (int kk = 0; kk < 4; ++kk)
#pragma unroll
        for (int j = 0; j < 4; ++j)
          acc[i][j] = fmaf(a[i][kk], bb[kk][j], acc[i][j]);
  }
  for (int k = k4max; k < K; ++k) {
    float4 w4 = *(const float4*)&W[k * D + tf];
    float bv[4] = {w4.x, w4.y, w4.z, w4.w};
#pragma unroll
    for (int i = 0; i < 4; ++i) {
      float av = xs[tm + i][k];
#pragma unroll
      for (int j = 0; j < 4; ++j) acc[i][j] = fmaf(av, bv[j], acc[i][j]);
    }
  }

#pragma unroll
  for (int i = 0; i < 4; ++i) {
    int v = v0 + tm + i;
    float s = ns[v];
    float4 o;
    o.x = acc[i][0] * s; o.y = acc[i][1] * s; o.z = acc[i][2] * s; o.w = acc[i][3] * s;
    *(float4*)&h[(size_t)v * D + tf] = o;
  }
}

// ---- aggregation: out[v] = relu( (sum_{dst==v} h[src]) * nd[v] + b ) --------
// 128 threads/node: 4 edge slots x (32 lanes * float4). 2x unroll per slot
// -> 8 independent 512B row-gathers in flight per block (latency hiding).
__global__ __launch_bounds__(128) void k_aggregate(const float* __restrict__ h,
                            const int* __restrict__ rowptr, const int* __restrict__ col,
                            const float* __restrict__ nd, const float* __restrict__ b,
                            float* __restrict__ out) {
  int v = blockIdx.x, t = threadIdx.x;
  int slot = t >> 5;
  int c = (t & 31) * 4;
  int beg = rowptr[v], end = rowptr[v + 1];

  float4 a0 = make_float4(0.f, 0.f, 0.f, 0.f);
  float4 a1 = make_float4(0.f, 0.f, 0.f, 0.f);
  int j = beg + slot;
  for (; j + 4 < end; j += 8) {
    int s0 = col[j];
    int s1 = col[j + 4];
    float4 r0 = *(const float4*)&h[(size_t)s0 * D + c];
    float4 r1 = *(const float4*)&h[(size_t)s1 * D + c];
    a0.x += r0.x; a0.y += r0.y; a0.z += r0.z; a0.w += r0.w;
    a1.x += r1.x; a1.y += r1.y; a1.z += r1.z; a1.w += r1.w;
  }
  if (j < end) {
    int s0 = col[j];
    float4 r0 = *(const float4*)&h[(size_t)s0 * D + c];
    a0.x += r0.x; a0.y += r0.y; a0.z += r0.z; a0.w += r0.w;
  }
  a0.x += a1.x; a0.y += a1.y; a0.z += a1.z; a0.w += a1.w;

  // slots {0,1} live in wave 0, {2,3} in wave 1: reduce across half-waves
  a0.x += __shfl_down(a0.x, 32, 64);
  a0.y += __shfl_down(a0.y, 32, 64);
  a0.z += __shfl_down(a0.z, 32, 64);
  a0.w += __shfl_down(a0.w, 32, 64);

  __shared__ float sred[32 * 4];
  if (t >= 64 && t < 96) *(float4*)&sred[(t - 64) * 4] = a0;
  __syncthreads();
  if (t < 32) {
    float4 o = *(const float4*)&sred[t * 4];
    a0.x += o.x; a0.y += o.y; a0.z += o.z; a0.w += o.w;
    float s = nd[v];
    float4 r;
    r.x = fmaxf(fmaf(a0.x, s, b[c + 0]), 0.f);
    r.y = fmaxf(fmaf(a0.y, s, b[c + 1]), 0.f);
    r.z = fmaxf(fmaf(a0.z, s, b[c + 2]), 0.f);
    r.w = fmaxf(fmaf(a0.w, s, b[c + 3]), 0.f);
    *(float4*)&out[(size_t)v * D + c] = r;
  }
}

// ---- segment mean: 256 threads/graph, 8 slots x float4, 2x unroll -----------
__global__ __launch_bounds__(256) void k_seg_mean(const float* __restrict__ x,
                           const int* __restrict__ rowptr, const int* __restrict__ list,
                           float* __restrict__ out) {
  int g = blockIdx.x, t = threadIdx.x;
  int slot = t >> 5;
  int c = (t & 31) * 4;
  int beg = rowptr[g], end = rowptr[g + 1];

  float4 a0 = make_float4(0.f, 0.f, 0.f, 0.f);
  float4 a1 = make_float4(0.f, 0.f, 0.f, 0.f);
  int j = beg + slot;
  for (; j + 8 < end; j += 16) {
    int s0 = list[j];
    int s1 = list[j + 8];
    float4 r0 = *(const float4*)&x[(size_t)s0 * D + c];
    float4 r1 = *(const float4*)&x[(size_t)s1 * D + c];
    a0.x += r0.x; a0.y += r0.y; a0.z += r0.z; a0.w += r0.w;
    a1.x += r1.x; a1.y += r1.y; a1.z += r1.z; a1.w += r1.w;
  }
  if (j < end) {
    int s0 = list[j];
    float4 r0 = *(const float4*)&x[(size_t)s0 * D + c];
    a0.x += r0.x; a0.y += r0.y; a0.z += r0.z; a0.w += r0.w;
  }
  a0.x += a1.x; a0.y += a1.y; a0.z += a1.z; a0.w += a1.w;

  // pairwise reduce slots within each wave (4 waves -> 4 partials)
  a0.x += __shfl_down(a0.x, 32, 64);
  a0.y += __shfl_down(a0.y, 32, 64);
  a0.z += __shfl_down(a0.z, 32, 64);
  a0.w += __shfl_down(a0.w, 32, 64);

  __shared__ float sred[4][32 * 4];
  int wid = t >> 6, lane = t & 63;
  if (lane < 32) *(float4*)&sred[wid][lane * 4] = a0;
  __syncthreads();
  if (t < 32) {
    float4 s0 = *(const float4*)&sred[0][t * 4];
    float4 s1 = *(const float4*)&sred[1][t * 4];
    float4 s2 = *(const float4*)&sred[2][t * 4];
    float4 s3 = *(const float4*)&sred[3][t * 4];
    float inv = 1.f / fmaxf((float)(end - beg), 1.f);
    float4 r;
    r.x = (s0.x + s1.x + s2.x + s3.x) * inv;
    r.y = (s0.y + s1.y + s2.y + s3.y) * inv;
    r.z = (s0.z + s1.z + s2.z + s3.z) * inv;
    r.w = (s0.w + s1.w + s2.w + s3.w) * inv;
    *(float4*)&out[(size_t)g * D + c] = r;
  }
}

__global__ void k_mlp(const float* __restrict__ cg, const float* __restrict__ pg,
                      const float* __restrict__ Wf1, const float* __restrict__ bf1,
                      const float* __restrict__ Wf2, const float* __restrict__ bf2,
                      float* __restrict__ out) {
  __shared__ float xs[256];
  __shared__ float red[128];
  int b = blockIdx.x, t = threadIdx.x;
  xs[t] = cg[b * D + t];
  xs[128 + t] = pg[b * D + t];
  __syncthreads();
  float acc = bf1[t];
  for (int k = 0; k < 256; ++k) acc = fmaf(xs[k], Wf1[k * D + t], acc);
  float hv = fmaxf(acc, 0.f);
  red[t] = hv * Wf2[t];
  for (int d = 64; d > 0; d >>= 1) {
    __syncthreads();
    if (t < d) red[t] += red[t + d];
  }
  if (t == 0) out[b] = red[0] + bf2[0];
}

// ---- launch -----------------------------------------------------------------

extern "C" void kernel_launch(void* const* d_in, const int* in_sizes, int n_in,
                              void* d_out, int out_size, void* d_ws, size_t ws_size,
                              hipStream_t stream) {
  const float* compound_feat = (const float*)d_in[0];
  const float* protein_feat  = (const float*)d_in[1];
  const int* c_src = (const int*)d_in[2];
  const int* c_dst = (const int*)d_in[3];
  const int* p_src = (const int*)d_in[4];
  const int* p_dst = (const int*)d_in[5];
  const int* c_gid = (const int*)d_in[6];
  const int* p_gid = (const int*)d_in[7];
  const float* Wc1 = (const float*)d_in[8];  const float* bc1 = (const float*)d_in[9];
  const float* Wc2 = (const float*)d_in[10]; const float* bc2 = (const float*)d_in[11];
  const float* Wp1 = (const float*)d_in[12]; const float* bp1 = (const float*)d_in[13];
  const float* Wp2 = (const float*)d_in[14]; const float* bp2 = (const float*)d_in[15];
  const float* Wf1 = (const float*)d_in[16]; const float* bf1 = (const float*)d_in[17];
  const float* Wf2 = (const float*)d_in[18]; const float* bf2 = (const float*)d_in[19];
  float* out = (float*)d_out;

  const int EC = in_sizes[2], EP = in_sizes[4];
  const int NC = in_sizes[6], NP = in_sizes[7];
  const int B  = out_size;
  const int KC = in_sizes[0] / NC;

  char* ws = (char*)d_ws;
  size_t off = 0;
  auto alloc = [&](size_t bytes) -> void* {
    void* p = ws + off;
    off += (bytes + 255) & ~(size_t)255;
    return p;
  };

  int* c_outdeg = (int*)alloc((size_t)NC * 4);
  int* c_indeg  = (int*)alloc((size_t)NC * 4);
  int* c_cnt    = (int*)alloc((size_t)NC * 4);
  int* p_outdeg = (int*)alloc((size_t)NP * 4);
  int* p_indeg  = (int*)alloc((size_t)NP * 4);
  int* p_cnt    = (int*)alloc((size_t)NP * 4);
  int* cg_hist  = (int*)alloc((size_t)B * 4);
  int* cg_cnt   = (int*)alloc((size_t)B * 4);
  int* pg_hist  = (int*)alloc((size_t)B * 4);
  int* pg_cnt   = (int*)alloc((size_t)B * 4);
  size_t zero_bytes = off;

  float* c_ns = (float*)alloc((size_t)NC * 4);
  float* c_nd = (float*)alloc((size_t)NC * 4);
  float* p_ns = (float*)alloc((size_t)NP * 4);
  float* p_nd = (float*)alloc((size_t)NP * 4);
  int* c_rowptr  = (int*)alloc((size_t)(NC + 1) * 4);
  int* p_rowptr  = (int*)alloc((size_t)(NP + 1) * 4);
  int* cg_rowptr = (int*)alloc((size_t)(B + 1) * 4);
  int* pg_rowptr = (int*)alloc((size_t)(B + 1) * 4);
  int* c_part  = (int*)alloc(64 * 4);
  int* p_part  = (int*)alloc(64 * 4);
  int* cg_part = (int*)alloc(64 * 4);
  int* pg_part = (int*)alloc(64 * 4);
  int* c_col   = (int*)alloc((size_t)EC * 4);
  int* p_col   = (int*)alloc((size_t)EP * 4);
  int* cg_list = (int*)alloc((size_t)NC * 4);
  int* pg_list = (int*)alloc((size_t)NP * 4);
  float* c_h = (float*)alloc((size_t)NC * D * 4);
  float* c_m = (float*)alloc((size_t)NC * D * 4);
  float* p_h = (float*)alloc((size_t)NP * D * 4);
  float* p_m = (float*)alloc((size_t)NP * D * 4);
  float* cg = (float*)alloc((size_t)B * D * 4);
  float* pg = (float*)alloc((size_t)B * D * 4);
  (void)ws_size; (void)n_in;

  hipMemsetAsync((void*)c_outdeg, 0, zero_bytes, stream);

  const int tb = 256;
  k_degrees<<<(EC + tb - 1) / tb, tb, 0, stream>>>(c_src, c_dst, c_outdeg, c_indeg, EC);
  k_degrees<<<(EP + tb - 1) / tb, tb, 0, stream>>>(p_src, p_dst, p_outdeg, p_indeg, EP);
  k_hist<<<(NC + tb - 1) / tb, tb, 0, stream>>>(c_gid, cg_hist, NC);
  k_hist<<<(NP + tb - 1) / tb, tb, 0, stream>>>(p_gid, pg_hist, NP);
  k_norms<<<(NC + tb - 1) / tb, tb, 0, stream>>>(c_outdeg, c_indeg, c_ns, c_nd, NC);
  k_norms<<<(NP + tb - 1) / tb, tb, 0, stream>>>(p_outdeg, p_indeg, p_ns, p_nd, NP);

  {
    int nbc = (NC + SCH - 1) / SCH, nbp = (NP + SCH - 1) / SCH, nbb = (B + SCH - 1) / SCH;
    k_scan_part<<<nbc, 256, 0, stream>>>(c_indeg, c_part, NC);
    k_scan_part<<<nbp, 256, 0, stream>>>(p_indeg, p_part, NP);
    k_scan_part<<<nbb, 256, 0, stream>>>(cg_hist, cg_part, B);
    k_scan_part<<<nbb, 256, 0, stream>>>(pg_hist, pg_part, B);
    k_scan_top<<<1, 64, 0, stream>>>(c_part, nbc, c_rowptr, NC);
    k_scan_top<<<1, 64, 0, stream>>>(p_part, nbp, p_rowptr, NP);
    k_scan_top<<<1, 64, 0, stream>>>(cg_part, nbb, cg_rowptr, B);
    k_scan_top<<<1, 64, 0, stream>>>(pg_part, nbb, pg_rowptr, B);
    k_scan_down<<<nbc, 256, 0, stream>>>(c_indeg, c_part, c_rowptr, NC);
    k_scan_down<<<nbp, 256, 0, stream>>>(p_indeg, p_part, p_rowptr, NP);
    k_scan_down<<<nbb, 256, 0, stream>>>(cg_hist, cg_part, cg_rowptr, B);
    k_scan_down<<<nbb, 256, 0, stream>>>(pg_hist, pg_part, pg_rowptr, B);
  }

  k_build_col<<<(EC + tb - 1) / tb, tb, 0, stream>>>(c_src, c_dst, c_rowptr, c_cnt, c_col, EC);
  k_build_col<<<(EP + tb - 1) / tb, tb, 0, stream>>>(p_src, p_dst, p_rowptr, p_cnt, p_col, EP);
  k_build_list<<<(NC + tb - 1) / tb, tb, 0, stream>>>(c_gid, cg_rowptr, cg_cnt, cg_list, NC);
  k_build_list<<<(NP + tb - 1) / tb, tb, 0, stream>>>(p_gid, pg_rowptr, pg_cnt, pg_list, NP);

  // compound tower
  k_nl_gemm<<<NC / 32, 256, 0, stream>>>(compound_feat, c_ns, Wc1, c_h, KC);
  k_aggregate<<<NC, 128, 0, stream>>>(c_h, c_rowptr, c_col, c_nd, bc1, c_m);
  k_nl_gemm<<<NC / 32, 256, 0, stream>>>(c_m, c_ns, Wc2, c_h, D);
  k_aggregate<<<NC, 128, 0, stream>>>(c_h, c_rowptr, c_col, c_nd, bc2, c_m);
  k_seg_mean<<<B, 256, 0, stream>>>(c_m, cg_rowptr, cg_list, cg);

  // protein tower
  k_nl_gemm<<<NP / 32, 256, 0, stream>>>(protein_feat, p_ns, Wp1, p_h, D);
  k_aggregate<<<NP, 128, 0, stream>>>(p_h, p_rowptr, p_col, p_nd, bp1, p_m);
  k_nl_gemm<<<NP / 32, 256, 0, stream>>>(p_m, p_ns, Wp2, p_h, D);
  k_aggregate<<<NP, 128, 0, stream>>>(p_h, p_rowptr, p_col, p_nd, bp2, p_m);
  k_seg_mean<<<B, 256, 0, stream>>>(p_m, pg_rowptr, pg_list, pg);

  k_mlp<<<B, D, 0, stream>>>(cg, pg, Wf1, bf1, Wf2, bf2, out);
}

// Round 4
// 971.926 us; speedup vs baseline: 2.1664x; 1.2346x over previous
//
#include <hip/hip_runtime.h>

#define D 128
#define KP 132      // padded LDS row stride for x tile
#define SCH 4096    // elements per scan block
#define NBLK 256    // blocks per level-1 distribution

// ---- hierarchical exclusive scan (3 phases) ---------------------------------

__global__ void k_scan_part(const int* __restrict__ deg, int* __restrict__ part, int n) {
  int b = blockIdx.x, t = threadIdx.x;
  int base = b * SCH;
  int s = 0;
  for (int i = t; i < SCH; i += 256) {
    int idx = base + i;
    if (idx < n) s += deg[idx];
  }
  __shared__ int red[256];
  red[t] = s;
  __syncthreads();
  for (int d = 128; d > 0; d >>= 1) {
    if (t < d) red[t] += red[t + d];
    __syncthreads();
  }
  if (t == 0) part[b] = red[0];
}

__global__ void k_scan_top(int* __restrict__ part, int nb, int* __restrict__ rowptr, int n) {
  if (threadIdx.x == 0) {
    int run = 0;
    for (int i = 0; i < nb; ++i) { int v = part[i]; part[i] = run; run += v; }
    rowptr[n] = run;
  }
}

__global__ void k_scan_down(const int* __restrict__ deg, const int* __restrict__ part,
                            int* __restrict__ rowptr, int n) {
  int b = blockIdx.x, t = threadIdx.x;
  int lane = t & 63, wid = t >> 6;
  __shared__ int wsum[4];
  int base = b * SCH;
  int offset = part[b];
  int idx0 = base + t * 16;
  int v[16];
  int s = 0;
#pragma unroll
  for (int i = 0; i < 16; ++i) {
    int idx = idx0 + i;
    v[i] = (idx < n) ? deg[idx] : 0;
    s += v[i];
  }
  int inc = s;
  for (int d = 1; d < 64; d <<= 1) {
    int u = __shfl_up(inc, d, 64);
    if (lane >= d) inc += u;
  }
  if (lane == 63) wsum[wid] = inc;
  __syncthreads();
  int woff = 0;
  for (int w = 0; w < wid; ++w) woff += wsum[w];
  int ex = offset + woff + inc - s;
#pragma unroll
  for (int i = 0; i < 16; ++i) {
    int idx = idx0 + i;
    if (idx < n) rowptr[idx] = ex;
    ex += v[i];
  }
}

// ---- atomic-free 2-level distribution ---------------------------------------
// Level 1: 256 coarse buckets (key >> shift), per-block private histogram flush.

__global__ __launch_bounds__(256) void k_l1hist(const int* __restrict__ keys, int n,
                                                int shift, int* __restrict__ H) {
  __shared__ int bins[256];
  int blk = blockIdx.x, t = threadIdx.x;
  bins[t] = 0;
  __syncthreads();
  int per = (n + NBLK - 1) / NBLK;
  int beg = blk * per, end = min(beg + per, n);
  for (int i = beg + t; i < end; i += 256)
    atomicAdd(&bins[keys[i] >> shift], 1);   // LDS atomic
  __syncthreads();
  H[t * NBLK + blk] = bins[t];               // bin-major, plain store
}

// key-only scatter (for out-degree counting)
__global__ __launch_bounds__(256) void k_l1scatter1(const int* __restrict__ keys, int n,
                                                    int shift, const int* __restrict__ base,
                                                    int* __restrict__ tmpk) {
  __shared__ int cur[256];
  int blk = blockIdx.x, t = threadIdx.x;
  cur[t] = base[t * NBLK + blk];
  __syncthreads();
  int per = (n + NBLK - 1) / NBLK;
  int beg = blk * per, end = min(beg + per, n);
  for (int i = beg + t; i < end; i += 256) {
    int k = keys[i];
    int pos = atomicAdd(&cur[k >> shift], 1);  // LDS atomic
    tmpk[pos] = k;
  }
}

// key+value scatter (for CSR build)
__global__ __launch_bounds__(256) void k_l1scatter2(const int* __restrict__ keys,
                                                    const int* __restrict__ vals, int n,
                                                    int shift, const int* __restrict__ base,
                                                    int* __restrict__ tmpk, int* __restrict__ tmpv) {
  __shared__ int cur[256];
  int blk = blockIdx.x, t = threadIdx.x;
  cur[t] = base[t * NBLK + blk];
  __syncthreads();
  int per = (n + NBLK - 1) / NBLK;
  int beg = blk * per, end = min(beg + per, n);
  for (int i = beg + t; i < end; i += 256) {
    int k = keys[i];
    int pos = atomicAdd(&cur[k >> shift], 1);
    tmpk[pos] = k;
    tmpv[pos] = vals[i];
  }
}

// index scatter (for gid lists: value = element index)
__global__ __launch_bounds__(256) void k_l1scatteridx(const int* __restrict__ keys, int n,
                                                      int shift, const int* __restrict__ base,
                                                      int* __restrict__ list) {
  __shared__ int cur[256];
  int blk = blockIdx.x, t = threadIdx.x;
  cur[t] = base[t * NBLK + blk];
  __syncthreads();
  int per = (n + NBLK - 1) / NBLK;
  int beg = blk * per, end = min(beg + per, n);
  for (int i = beg + t; i < end; i += 256) {
    int pos = atomicAdd(&cur[keys[i] >> shift], 1);
    list[pos] = i;
  }
}

// Level 2: one workgroup per coarse bucket; fine bins (<=512) in LDS.
__global__ __launch_bounds__(256) void k_l2count(const int* __restrict__ tmpk,
                                                 const int* __restrict__ base, int n,
                                                 int fine, int* __restrict__ deg) {
  __shared__ int bins[512];
  int b = blockIdx.x, t = threadIdx.x;
  for (int f = t; f < fine; f += 256) bins[f] = 0;
  __syncthreads();
  int beg = base[b * NBLK];
  int end = (b == NBLK - 1) ? n : base[(b + 1) * NBLK];
  for (int i = beg + t; i < end; i += 256)
    atomicAdd(&bins[tmpk[i] & (fine - 1)], 1);
  __syncthreads();
  for (int f = t; f < fine; f += 256)
    deg[b * fine + f] = bins[f];               // plain coalesced store
}

__global__ __launch_bounds__(256) void k_l2scatter(const int* __restrict__ tmpk,
                                                   const int* __restrict__ tmpv,
                                                   const int* __restrict__ base, int n,
                                                   const int* __restrict__ rowptr,
                                                   int shift, int fine, int* __restrict__ col) {
  __shared__ int cur[512];
  int b = blockIdx.x, t = threadIdx.x;
  int v0 = b << shift;
  for (int f = t; f < fine; f += 256) cur[f] = rowptr[v0 + f];
  __syncthreads();
  int beg = base[b * NBLK];
  int end = (b == NBLK - 1) ? n : base[(b + 1) * NBLK];
  for (int i = beg + t; i < end; i += 256) {
    int pos = atomicAdd(&cur[tmpk[i] & (fine - 1)], 1);
    col[pos] = tmpv[i];
  }
}

__global__ void k_norms(const int* __restrict__ outdeg, const int* __restrict__ indeg,
                        float* __restrict__ ns, float* __restrict__ nd, int n) {
  int i = blockIdx.x * blockDim.x + threadIdx.x;
  if (i < n) {
    ns[i] = rsqrtf(fmaxf((float)outdeg[i], 1.f));
    nd[i] = rsqrtf(fmaxf((float)indeg[i], 1.f));
  }
}

// ---- node-feature GEMM: h[v,:] = ns[v] * (x[v,:] @ W) -----------------------
__global__ __launch_bounds__(256) void k_nl_gemm(const float* __restrict__ x,
                                                 const float* __restrict__ ns,
                                                 const float* __restrict__ W,
                                                 float* __restrict__ h, int K) {
  __shared__ float xs[32][KP];
  int t = threadIdx.x;
  int v0 = blockIdx.x * 32;

  {
    int m = t >> 5, k = t & 31;
    for (int kk = k; kk < K; kk += 32)
      for (int mm = m; mm < 32; mm += 8)
        xs[mm][kk] = x[(size_t)(v0 + mm) * K + kk];
  }
  __syncthreads();

  int tm = (t >> 5) * 4;
  int tf = (t & 31) * 4;

  float acc[4][4];
#pragma unroll
  for (int i = 0; i < 4; ++i)
#pragma unroll
    for (int j = 0; j < 4; ++j) acc[i][j] = 0.f;

  int k4max = K & ~3;
  for (int k4 = 0; k4 < k4max; k4 += 4) {
    float a[4][4], bb[4][4];
#pragma unroll
    for (int kk = 0; kk < 4; ++kk) {
      float4 w4 = *(const float4*)&W[(k4 + kk) * D + tf];
      bb[kk][0] = w4.x; bb[kk][1] = w4.y; bb[kk][2] = w4.z; bb[kk][3] = w4.w;
    }
#pragma unroll
    for (int i = 0; i < 4; ++i) {
      float4 a4 = *(const float4*)&xs[tm + i][k4];
      a[i][0] = a4.x; a[i][1] = a4.y; a[i][2] = a4.z; a[i][3] = a4.w;
    }
#pragma unroll
    for (int i = 0; i < 4; ++i)
#pragma unroll
      for (int kk = 0; kk < 4; ++kk)
#pragma unroll
        for (int j = 0; j < 4; ++j)
          acc[i][j] = fmaf(a[i][kk], bb[kk][j], acc[i][j]);
  }
  for (int k = k4max; k < K; ++k) {
    float4 w4 = *(const float4*)&W[k * D + tf];
    float bv[4] = {w4.x, w4.y, w4.z, w4.w};
#pragma unroll
    for (int i = 0; i < 4; ++i) {
      float av = xs[tm + i][k];
#pragma unroll
      for (int j = 0; j < 4; ++j) acc[i][j] = fmaf(av, bv[j], acc[i][j]);
    }
  }

#pragma unroll
  for (int i = 0; i < 4; ++i) {
    int v = v0 + tm + i;
    float s = ns[v];
    float4 o;
    o.x = acc[i][0] * s; o.y = acc[i][1] * s; o.z = acc[i][2] * s; o.w = acc[i][3] * s;
    *(float4*)&h[(size_t)v * D + tf] = o;
  }
}

// ---- aggregation ------------------------------------------------------------
__global__ __launch_bounds__(128) void k_aggregate(const float* __restrict__ h,
                            const int* __restrict__ rowptr, const int* __restrict__ col,
                            const float* __restrict__ nd, const float* __restrict__ b,
                            float* __restrict__ out) {
  int v = blockIdx.x, t = threadIdx.x;
  int slot = t >> 5;
  int c = (t & 31) * 4;
  int beg = rowptr[v], end = rowptr[v + 1];

  float4 a0 = make_float4(0.f, 0.f, 0.f, 0.f);
  float4 a1 = make_float4(0.f, 0.f, 0.f, 0.f);
  int j = beg + slot;
  for (; j + 4 < end; j += 8) {
    int s0 = col[j];
    int s1 = col[j + 4];
    float4 r0 = *(const float4*)&h[(size_t)s0 * D + c];
    float4 r1 = *(const float4*)&h[(size_t)s1 * D + c];
    a0.x += r0.x; a0.y += r0.y; a0.z += r0.z; a0.w += r0.w;
    a1.x += r1.x; a1.y += r1.y; a1.z += r1.z; a1.w += r1.w;
  }
  if (j < end) {
    int s0 = col[j];
    float4 r0 = *(const float4*)&h[(size_t)s0 * D + c];
    a0.x += r0.x; a0.y += r0.y; a0.z += r0.z; a0.w += r0.w;
  }
  a0.x += a1.x; a0.y += a1.y; a0.z += a1.z; a0.w += a1.w;

  a0.x += __shfl_down(a0.x, 32, 64);
  a0.y += __shfl_down(a0.y, 32, 64);
  a0.z += __shfl_down(a0.z, 32, 64);
  a0.w += __shfl_down(a0.w, 32, 64);

  __shared__ float sred[32 * 4];
  if (t >= 64 && t < 96) *(float4*)&sred[(t - 64) * 4] = a0;
  __syncthreads();
  if (t < 32) {
    float4 o = *(const float4*)&sred[t * 4];
    a0.x += o.x; a0.y += o.y; a0.z += o.z; a0.w += o.w;
    float s = nd[v];
    float4 r;
    r.x = fmaxf(fmaf(a0.x, s, b[c + 0]), 0.f);
    r.y = fmaxf(fmaf(a0.y, s, b[c + 1]), 0.f);
    r.z = fmaxf(fmaf(a0.z, s, b[c + 2]), 0.f);
    r.w = fmaxf(fmaf(a0.w, s, b[c + 3]), 0.f);
    *(float4*)&out[(size_t)v * D + c] = r;
  }
}

// ---- segment mean: ranges come from the gid level-1 base array --------------
__global__ __launch_bounds__(256) void k_seg_mean(const float* __restrict__ x,
                           const int* __restrict__ gbase, int n,
                           const int* __restrict__ list, float* __restrict__ out) {
  int g = blockIdx.x, t = threadIdx.x;
  int slot = t >> 5;
  int c = (t & 31) * 4;
  int beg = gbase[g * NBLK];
  int end = (g == (int)gridDim.x - 1) ? n : gbase[(g + 1) * NBLK];

  float4 a0 = make_float4(0.f, 0.f, 0.f, 0.f);
  float4 a1 = make_float4(0.f, 0.f, 0.f, 0.f);
  int j = beg + slot;
  for (; j + 8 < end; j += 16) {
    int s0 = list[j];
    int s1 = list[j + 8];
    float4 r0 = *(const float4*)&x[(size_t)s0 * D + c];
    float4 r1 = *(const float4*)&x[(size_t)s1 * D + c];
    a0.x += r0.x; a0.y += r0.y; a0.z += r0.z; a0.w += r0.w;
    a1.x += r1.x; a1.y += r1.y; a1.z += r1.z; a1.w += r1.w;
  }
  if (j < end) {
    int s0 = list[j];
    float4 r0 = *(const float4*)&x[(size_t)s0 * D + c];
    a0.x += r0.x; a0.y += r0.y; a0.z += r0.z; a0.w += r0.w;
  }
  a0.x += a1.x; a0.y += a1.y; a0.z += a1.z; a0.w += a1.w;

  a0.x += __shfl_down(a0.x, 32, 64);
  a0.y += __shfl_down(a0.y, 32, 64);
  a0.z += __shfl_down(a0.z, 32, 64);
  a0.w += __shfl_down(a0.w, 32, 64);

  __shared__ float sred[4][32 * 4];
  int wid = t >> 6, lane = t & 63;
  if (lane < 32) *(float4*)&sred[wid][lane * 4] = a0;
  __syncthreads();
  if (t < 32) {
    float4 s0 = *(const float4*)&sred[0][t * 4];
    float4 s1 = *(const float4*)&sred[1][t * 4];
    float4 s2 = *(const float4*)&sred[2][t * 4];
    float4 s3 = *(const float4*)&sred[3][t * 4];
    float inv = 1.f / fmaxf((float)(end - beg), 1.f);
    float4 r;
    r.x = (s0.x + s1.x + s2.x + s3.x) * inv;
    r.y = (s0.y + s1.y + s2.y + s3.y) * inv;
    r.z = (s0.z + s1.z + s2.z + s3.z) * inv;
    r.w = (s0.w + s1.w + s2.w + s3.w) * inv;
    *(float4*)&out[(size_t)g * D + c] = r;
  }
}

__global__ void k_mlp(const float* __restrict__ cg, const float* __restrict__ pg,
                      const float* __restrict__ Wf1, const float* __restrict__ bf1,
                      const float* __restrict__ Wf2, const float* __restrict__ bf2,
                      float* __restrict__ out) {
  __shared__ float xs[256];
  __shared__ float red[128];
  int b = blockIdx.x, t = threadIdx.x;
  xs[t] = cg[b * D + t];
  xs[128 + t] = pg[b * D + t];
  __syncthreads();
  float acc = bf1[t];
  for (int k = 0; k < 256; ++k) acc = fmaf(xs[k], Wf1[k * D + t], acc);
  float hv = fmaxf(acc, 0.f);
  red[t] = hv * Wf2[t];
  for (int d = 64; d > 0; d >>= 1) {
    __syncthreads();
    if (t < d) red[t] += red[t + d];
  }
  if (t == 0) out[b] = red[0] + bf2[0];
}

// ---- launch -----------------------------------------------------------------

extern "C" void kernel_launch(void* const* d_in, const int* in_sizes, int n_in,
                              void* d_out, int out_size, void* d_ws, size_t ws_size,
                              hipStream_t stream) {
  const float* compound_feat = (const float*)d_in[0];
  const float* protein_feat  = (const float*)d_in[1];
  const int* c_src = (const int*)d_in[2];
  const int* c_dst = (const int*)d_in[3];
  const int* p_src = (const int*)d_in[4];
  const int* p_dst = (const int*)d_in[5];
  const int* c_gid = (const int*)d_in[6];
  const int* p_gid = (const int*)d_in[7];
  const float* Wc1 = (const float*)d_in[8];  const float* bc1 = (const float*)d_in[9];
  const float* Wc2 = (const float*)d_in[10]; const float* bc2 = (const float*)d_in[11];
  const float* Wp1 = (const float*)d_in[12]; const float* bp1 = (const float*)d_in[13];
  const float* Wp2 = (const float*)d_in[14]; const float* bp2 = (const float*)d_in[15];
  const float* Wf1 = (const float*)d_in[16]; const float* bf1 = (const float*)d_in[17];
  const float* Wf2 = (const float*)d_in[18]; const float* bf2 = (const float*)d_in[19];
  float* out = (float*)d_out;

  const int EC = in_sizes[2], EP = in_sizes[4];
  const int NC = in_sizes[6], NP = in_sizes[7];
  const int B  = out_size;
  const int KC = in_sizes[0] / NC;
  const int cshift = __builtin_ctz(NC / 256), cfine = NC / 256;   // 6, 64
  const int pshift = __builtin_ctz(NP / 256), pfine = NP / 256;   // 9, 512

  char* ws = (char*)d_ws;
  size_t off = 0;
  auto alloc = [&](size_t bytes) -> void* {
    void* p = ws + off;
    off += (bytes + 255) & ~(size_t)255;
    return p;
  };

  int* H       = (int*)alloc((size_t)256 * NBLK * 4);
  int* base    = (int*)alloc(((size_t)256 * NBLK + 1) * 4);
  int* baseg_c = (int*)alloc(((size_t)256 * NBLK + 1) * 4);
  int* baseg_p = (int*)alloc(((size_t)256 * NBLK + 1) * 4);
  int* spart   = (int*)alloc(64 * 4);
  int* tmpk    = (int*)alloc((size_t)EP * 4);
  int* tmpv    = (int*)alloc((size_t)EP * 4);
  int* c_outdeg = (int*)alloc((size_t)NC * 4);
  int* c_indeg  = (int*)alloc((size_t)NC * 4);
  int* p_outdeg = (int*)alloc((size_t)NP * 4);
  int* p_indeg  = (int*)alloc((size_t)NP * 4);
  float* c_ns = (float*)alloc((size_t)NC * 4);
  float* c_nd = (float*)alloc((size_t)NC * 4);
  float* p_ns = (float*)alloc((size_t)NP * 4);
  float* p_nd = (float*)alloc((size_t)NP * 4);
  int* c_rowptr = (int*)alloc((size_t)(NC + 1) * 4);
  int* p_rowptr = (int*)alloc((size_t)(NP + 1) * 4);
  int* c_col   = (int*)alloc((size_t)EC * 4);
  int* p_col   = (int*)alloc((size_t)EP * 4);
  int* cg_list = (int*)alloc((size_t)NC * 4);
  int* pg_list = (int*)alloc((size_t)NP * 4);
  float* c_h = (float*)alloc((size_t)NC * D * 4);
  float* c_m = (float*)alloc((size_t)NC * D * 4);
  float* p_h = (float*)alloc((size_t)NP * D * 4);
  float* p_m = (float*)alloc((size_t)NP * D * 4);
  float* cg = (float*)alloc((size_t)B * D * 4);
  float* pg = (float*)alloc((size_t)B * D * 4);
  (void)ws_size; (void)n_in;

  auto scan = [&](const int* in, int* outp, int n) {
    int nb = (n + SCH - 1) / SCH;
    k_scan_part<<<nb, 256, 0, stream>>>(in, spart, n);
    k_scan_top<<<1, 64, 0, stream>>>(spart, nb, outp, n);
    k_scan_down<<<nb, 256, 0, stream>>>(in, spart, outp, n);
  };
  const int HN = 256 * NBLK;

  // ---- compound preprocessing (no global atomics) ----
  k_l1hist<<<NBLK, 256, 0, stream>>>(c_src, EC, cshift, H);
  scan(H, base, HN);
  k_l1scatter1<<<NBLK, 256, 0, stream>>>(c_src, EC, cshift, base, tmpk);
  k_l2count<<<NBLK, 256, 0, stream>>>(tmpk, base, EC, cfine, c_outdeg);

  k_l1hist<<<NBLK, 256, 0, stream>>>(c_dst, EC, cshift, H);
  scan(H, base, HN);
  k_l1scatter2<<<NBLK, 256, 0, stream>>>(c_dst, c_src, EC, cshift, base, tmpk, tmpv);
  k_l2count<<<NBLK, 256, 0, stream>>>(tmpk, base, EC, cfine, c_indeg);
  scan(c_indeg, c_rowptr, NC);
  k_l2scatter<<<NBLK, 256, 0, stream>>>(tmpk, tmpv, base, EC, c_rowptr, cshift, cfine, c_col);
  k_norms<<<(NC + 255) / 256, 256, 0, stream>>>(c_outdeg, c_indeg, c_ns, c_nd, NC);

  k_l1hist<<<NBLK, 256, 0, stream>>>(c_gid, NC, 0, H);
  scan(H, baseg_c, HN);
  k_l1scatteridx<<<NBLK, 256, 0, stream>>>(c_gid, NC, 0, baseg_c, cg_list);

  // ---- protein preprocessing ----
  k_l1hist<<<NBLK, 256, 0, stream>>>(p_src, EP, pshift, H);
  scan(H, base, HN);
  k_l1scatter1<<<NBLK, 256, 0, stream>>>(p_src, EP, pshift, base, tmpk);
  k_l2count<<<NBLK, 256, 0, stream>>>(tmpk, base, EP, pfine, p_outdeg);

  k_l1hist<<<NBLK, 256, 0, stream>>>(p_dst, EP, pshift, H);
  scan(H, base, HN);
  k_l1scatter2<<<NBLK, 256, 0, stream>>>(p_dst, p_src, EP, pshift, base, tmpk, tmpv);
  k_l2count<<<NBLK, 256, 0, stream>>>(tmpk, base, EP, pfine, p_indeg);
  scan(p_indeg, p_rowptr, NP);
  k_l2scatter<<<NBLK, 256, 0, stream>>>(tmpk, tmpv, base, EP, p_rowptr, pshift, pfine, p_col);
  k_norms<<<(NP + 255) / 256, 256, 0, stream>>>(p_outdeg, p_indeg, p_ns, p_nd, NP);

  k_l1hist<<<NBLK, 256, 0, stream>>>(p_gid, NP, 0, H);
  scan(H, baseg_p, HN);
  k_l1scatteridx<<<NBLK, 256, 0, stream>>>(p_gid, NP, 0, baseg_p, pg_list);

  // ---- compound tower ----
  k_nl_gemm<<<NC / 32, 256, 0, stream>>>(compound_feat, c_ns, Wc1, c_h, KC);
  k_aggregate<<<NC, 128, 0, stream>>>(c_h, c_rowptr, c_col, c_nd, bc1, c_m);
  k_nl_gemm<<<NC / 32, 256, 0, stream>>>(c_m, c_ns, Wc2, c_h, D);
  k_aggregate<<<NC, 128, 0, stream>>>(c_h, c_rowptr, c_col, c_nd, bc2, c_m);
  k_seg_mean<<<B, 256, 0, stream>>>(c_m, baseg_c, NC, cg_list, cg);

  // ---- protein tower ----
  k_nl_gemm<<<NP / 32, 256, 0, stream>>>(protein_feat, p_ns, Wp1, p_h, D);
  k_aggregate<<<NP, 128, 0, stream>>>(p_h, p_rowptr, p_col, p_nd, bp1, p_m);
  k_nl_gemm<<<NP / 32, 256, 0, stream>>>(p_m, p_ns, Wp2, p_h, D);
  k_aggregate<<<NP, 128, 0, stream>>>(p_h, p_rowptr, p_col, p_nd, bp2, p_m);
  k_seg_mean<<<B, 256, 0, stream>>>(p_m, baseg_p, NP, pg_list, pg);

  k_mlp<<<B, D, 0, stream>>>(cg, pg, Wf1, bf1, Wf2, bf2, out);
}

// Round 5
// 889.757 us; speedup vs baseline: 2.3664x; 1.0923x over previous
//
#include <hip/hip_runtime.h>
#include <hip/hip_fp16.h>

#define D 128
#define KP 132      // padded LDS row stride for x tile
#define SCH 4096    // elements per scan block
#define NBLK 256    // blocks per level-1 distribution

// ---- hierarchical exclusive scan (3 phases) ---------------------------------

__global__ void k_scan_part(const int* __restrict__ deg, int* __restrict__ part, int n) {
  int b = blockIdx.x, t = threadIdx.x;
  int base = b * SCH;
  int s = 0;
  for (int i = t; i < SCH; i += 256) {
    int idx = base + i;
    if (idx < n) s += deg[idx];
  }
  __shared__ int red[256];
  red[t] = s;
  __syncthreads();
  for (int d = 128; d > 0; d >>= 1) {
    if (t < d) red[t] += red[t + d];
    __syncthreads();
  }
  if (t == 0) part[b] = red[0];
}

__global__ void k_scan_top(int* __restrict__ part, int nb, int* __restrict__ rowptr, int n) {
  if (threadIdx.x == 0) {
    int run = 0;
    for (int i = 0; i < nb; ++i) { int v = part[i]; part[i] = run; run += v; }
    rowptr[n] = run;
  }
}

__global__ void k_scan_down(const int* __restrict__ deg, const int* __restrict__ part,
                            int* __restrict__ rowptr, int n) {
  int b = blockIdx.x, t = threadIdx.x;
  int lane = t & 63, wid = t >> 6;
  __shared__ int wsum[4];
  int base = b * SCH;
  int offset = part[b];
  int idx0 = base + t * 16;
  int v[16];
  int s = 0;
#pragma unroll
  for (int i = 0; i < 16; ++i) {
    int idx = idx0 + i;
    v[i] = (idx < n) ? deg[idx] : 0;
    s += v[i];
  }
  int inc = s;
  for (int d = 1; d < 64; d <<= 1) {
    int u = __shfl_up(inc, d, 64);
    if (lane >= d) inc += u;
  }
  if (lane == 63) wsum[wid] = inc;
  __syncthreads();
  int woff = 0;
  for (int w = 0; w < wid; ++w) woff += wsum[w];
  int ex = offset + woff + inc - s;
#pragma unroll
  for (int i = 0; i < 16; ++i) {
    int idx = idx0 + i;
    if (idx < n) rowptr[idx] = ex;
    ex += v[i];
  }
}

// ---- atomic-free 2-level distribution ---------------------------------------

__global__ __launch_bounds__(256) void k_l1hist(const int* __restrict__ keys, int n,
                                                int shift, int* __restrict__ H) {
  __shared__ int bins[256];
  int blk = blockIdx.x, t = threadIdx.x;
  bins[t] = 0;
  __syncthreads();
  int per = (n + NBLK - 1) / NBLK;
  int beg = blk * per, end = min(beg + per, n);
  for (int i = beg + t; i < end; i += 256)
    atomicAdd(&bins[keys[i] >> shift], 1);
  __syncthreads();
  H[t * NBLK + blk] = bins[t];
}

__global__ __launch_bounds__(256) void k_l1scatter1(const int* __restrict__ keys, int n,
                                                    int shift, const int* __restrict__ base,
                                                    int* __restrict__ tmpk) {
  __shared__ int cur[256];
  int blk = blockIdx.x, t = threadIdx.x;
  cur[t] = base[t * NBLK + blk];
  __syncthreads();
  int per = (n + NBLK - 1) / NBLK;
  int beg = blk * per, end = min(beg + per, n);
  for (int i = beg + t; i < end; i += 256) {
    int k = keys[i];
    int pos = atomicAdd(&cur[k >> shift], 1);
    tmpk[pos] = k;
  }
}

__global__ __launch_bounds__(256) void k_l1scatter2(const int* __restrict__ keys,
                                                    const int* __restrict__ vals, int n,
                                                    int shift, const int* __restrict__ base,
                                                    int* __restrict__ tmpk, int* __restrict__ tmpv) {
  __shared__ int cur[256];
  int blk = blockIdx.x, t = threadIdx.x;
  cur[t] = base[t * NBLK + blk];
  __syncthreads();
  int per = (n + NBLK - 1) / NBLK;
  int beg = blk * per, end = min(beg + per, n);
  for (int i = beg + t; i < end; i += 256) {
    int k = keys[i];
    int pos = atomicAdd(&cur[k >> shift], 1);
    tmpk[pos] = k;
    tmpv[pos] = vals[i];
  }
}

__global__ __launch_bounds__(256) void k_l1scatteridx(const int* __restrict__ keys, int n,
                                                      int shift, const int* __restrict__ base,
                                                      int* __restrict__ list) {
  __shared__ int cur[256];
  int blk = blockIdx.x, t = threadIdx.x;
  cur[t] = base[t * NBLK + blk];
  __syncthreads();
  int per = (n + NBLK - 1) / NBLK;
  int beg = blk * per, end = min(beg + per, n);
  for (int i = beg + t; i < end; i += 256) {
    int pos = atomicAdd(&cur[keys[i] >> shift], 1);
    list[pos] = i;
  }
}

__global__ __launch_bounds__(256) void k_l2count(const int* __restrict__ tmpk,
                                                 const int* __restrict__ base, int n,
                                                 int fine, int* __restrict__ deg) {
  __shared__ int bins[512];
  int b = blockIdx.x, t = threadIdx.x;
  for (int f = t; f < fine; f += 256) bins[f] = 0;
  __syncthreads();
  int beg = base[b * NBLK];
  int end = (b == NBLK - 1) ? n : base[(b + 1) * NBLK];
  for (int i = beg + t; i < end; i += 256)
    atomicAdd(&bins[tmpk[i] & (fine - 1)], 1);
  __syncthreads();
  for (int f = t; f < fine; f += 256)
    deg[b * fine + f] = bins[f];
}

__global__ __launch_bounds__(256) void k_l2scatter(const int* __restrict__ tmpk,
                                                   const int* __restrict__ tmpv,
                                                   const int* __restrict__ base, int n,
                                                   const int* __restrict__ rowptr,
                                                   int shift, int fine, int* __restrict__ col) {
  __shared__ int cur[512];
  int b = blockIdx.x, t = threadIdx.x;
  int v0 = b << shift;
  for (int f = t; f < fine; f += 256) cur[f] = rowptr[v0 + f];
  __syncthreads();
  int beg = base[b * NBLK];
  int end = (b == NBLK - 1) ? n : base[(b + 1) * NBLK];
  for (int i = beg + t; i < end; i += 256) {
    int pos = atomicAdd(&cur[tmpk[i] & (fine - 1)], 1);
    col[pos] = tmpv[i];
  }
}

__global__ void k_norms(const int* __restrict__ outdeg, const int* __restrict__ indeg,
                        float* __restrict__ ns, float* __restrict__ nd, int n) {
  int i = blockIdx.x * blockDim.x + threadIdx.x;
  if (i < n) {
    ns[i] = rsqrtf(fmaxf((float)outdeg[i], 1.f));
    nd[i] = rsqrtf(fmaxf((float)indeg[i], 1.f));
  }
}

// ---- node-feature GEMM: h[v,:] = fp16( ns[v] * (x[v,:] @ W) ) ----------------
__global__ __launch_bounds__(256) void k_nl_gemm(const float* __restrict__ x,
                                                 const float* __restrict__ ns,
                                                 const float* __restrict__ W,
                                                 __half* __restrict__ h, int K) {
  __shared__ float xs[32][KP];
  int t = threadIdx.x;
  int v0 = blockIdx.x * 32;

  {
    int m = t >> 5, k = t & 31;
    for (int kk = k; kk < K; kk += 32)
      for (int mm = m; mm < 32; mm += 8)
        xs[mm][kk] = x[(size_t)(v0 + mm) * K + kk];
  }
  __syncthreads();

  int tm = (t >> 5) * 4;
  int tf = (t & 31) * 4;

  float acc[4][4];
#pragma unroll
  for (int i = 0; i < 4; ++i)
#pragma unroll
    for (int j = 0; j < 4; ++j) acc[i][j] = 0.f;

  int k4max = K & ~3;
  for (int k4 = 0; k4 < k4max; k4 += 4) {
    float a[4][4], bb[4][4];
#pragma unroll
    for (int kk = 0; kk < 4; ++kk) {
      float4 w4 = *(const float4*)&W[(k4 + kk) * D + tf];
      bb[kk][0] = w4.x; bb[kk][1] = w4.y; bb[kk][2] = w4.z; bb[kk][3] = w4.w;
    }
#pragma unroll
    for (int i = 0; i < 4; ++i) {
      float4 a4 = *(const float4*)&xs[tm + i][k4];
      a[i][0] = a4.x; a[i][1] = a4.y; a[i][2] = a4.z; a[i][3] = a4.w;
    }
#pragma unroll
    for (int i = 0; i < 4; ++i)
#pragma unroll
      for (int kk = 0; kk < 4; ++kk)
#pragma unroll
        for (int j = 0; j < 4; ++j)
          acc[i][j] = fmaf(a[i][kk], bb[kk][j], acc[i][j]);
  }
  for (int k = k4max; k < K; ++k) {
    float4 w4 = *(const float4*)&W[k * D + tf];
    float bv[4] = {w4.x, w4.y, w4.z, w4.w};
#pragma unroll
    for (int i = 0; i < 4; ++i) {
      float av = xs[tm + i][k];
#pragma unroll
      for (int j = 0; j < 4; ++j) acc[i][j] = fmaf(av, bv[j], acc[i][j]);
    }
  }

#pragma unroll
  for (int i = 0; i < 4; ++i) {
    int v = v0 + tm + i;
    float s = ns[v];
    union { __half2 h2[2]; uint2 u; } pk;
    __half2 p0, p1;
    p0.x = __float2half_rn(acc[i][0] * s); p0.y = __float2half_rn(acc[i][1] * s);
    p1.x = __float2half_rn(acc[i][2] * s); p1.y = __float2half_rn(acc[i][3] * s);
    pk.h2[0] = p0; pk.h2[1] = p1;
    *(uint2*)&h[(size_t)v * D + tf] = pk.u;
  }
}

// ---- aggregation: fp16 gather, fp32 accumulate ------------------------------
// 128 threads/node: 4 slots x (32 lanes * half4=8B). 4x unroll -> 16 rows in flight.
__device__ __forceinline__ void acc_half4(float4& a, const __half* p) {
  uint2 r = *(const uint2*)p;
  __half2 q0 = *(__half2*)&r.x;
  __half2 q1 = *(__half2*)&r.y;
  float2 f0 = __half22float2(q0);
  float2 f1 = __half22float2(q1);
  a.x += f0.x; a.y += f0.y; a.z += f1.x; a.w += f1.y;
}

template <bool HALF_OUT>
__global__ __launch_bounds__(128) void k_aggregate(const __half* __restrict__ h,
                            const int* __restrict__ rowptr, const int* __restrict__ col,
                            const float* __restrict__ nd, const float* __restrict__ b,
                            void* __restrict__ out) {
  int v = blockIdx.x, t = threadIdx.x;
  int slot = t >> 5;
  int c = (t & 31) * 4;
  int beg = rowptr[v], end = rowptr[v + 1];

  float4 a0 = make_float4(0.f, 0.f, 0.f, 0.f);
  float4 a1 = make_float4(0.f, 0.f, 0.f, 0.f);
  float4 a2 = make_float4(0.f, 0.f, 0.f, 0.f);
  float4 a3 = make_float4(0.f, 0.f, 0.f, 0.f);
  int j = beg + slot;
  for (; j + 12 < end; j += 16) {
    int s0 = col[j], s1 = col[j + 4], s2 = col[j + 8], s3 = col[j + 12];
    acc_half4(a0, h + (size_t)s0 * D + c);
    acc_half4(a1, h + (size_t)s1 * D + c);
    acc_half4(a2, h + (size_t)s2 * D + c);
    acc_half4(a3, h + (size_t)s3 * D + c);
  }
  for (; j < end; j += 4)
    acc_half4(a0, h + (size_t)col[j] * D + c);
  a0.x += a1.x + a2.x + a3.x;
  a0.y += a1.y + a2.y + a3.y;
  a0.z += a1.z + a2.z + a3.z;
  a0.w += a1.w + a2.w + a3.w;

  a0.x += __shfl_down(a0.x, 32, 64);
  a0.y += __shfl_down(a0.y, 32, 64);
  a0.z += __shfl_down(a0.z, 32, 64);
  a0.w += __shfl_down(a0.w, 32, 64);

  __shared__ float sred[32 * 4];
  if (t >= 64 && t < 96) *(float4*)&sred[(t - 64) * 4] = a0;
  __syncthreads();
  if (t < 32) {
    float4 o = *(const float4*)&sred[t * 4];
    a0.x += o.x; a0.y += o.y; a0.z += o.z; a0.w += o.w;
    float s = nd[v];
    float4 r;
    r.x = fmaxf(fmaf(a0.x, s, b[c + 0]), 0.f);
    r.y = fmaxf(fmaf(a0.y, s, b[c + 1]), 0.f);
    r.z = fmaxf(fmaf(a0.z, s, b[c + 2]), 0.f);
    r.w = fmaxf(fmaf(a0.w, s, b[c + 3]), 0.f);
    if (HALF_OUT) {
      union { __half2 h2[2]; uint2 u; } pk;
      __half2 p0, p1;
      p0.x = __float2half_rn(r.x); p0.y = __float2half_rn(r.y);
      p1.x = __float2half_rn(r.z); p1.y = __float2half_rn(r.w);
      pk.h2[0] = p0; pk.h2[1] = p1;
      *(uint2*)&((__half*)out)[(size_t)v * D + c] = pk.u;
    } else {
      *(float4*)&((float*)out)[(size_t)v * D + c] = r;
    }
  }
}

// ---- segment mean over fp16 rows --------------------------------------------
__global__ __launch_bounds__(256) void k_seg_mean(const __half* __restrict__ x,
                           const int* __restrict__ gbase, int n,
                           const int* __restrict__ list, float* __restrict__ out) {
  int g = blockIdx.x, t = threadIdx.x;
  int slot = t >> 5;
  int c = (t & 31) * 4;
  int beg = gbase[g * NBLK];
  int end = (g == (int)gridDim.x - 1) ? n : gbase[(g + 1) * NBLK];

  float4 a0 = make_float4(0.f, 0.f, 0.f, 0.f);
  float4 a1 = make_float4(0.f, 0.f, 0.f, 0.f);
  int j = beg + slot;
  for (; j + 8 < end; j += 16) {
    int s0 = list[j], s1 = list[j + 8];
    acc_half4(a0, x + (size_t)s0 * D + c);
    acc_half4(a1, x + (size_t)s1 * D + c);
  }
  if (j < end)
    acc_half4(a0, x + (size_t)list[j] * D + c);
  a0.x += a1.x; a0.y += a1.y; a0.z += a1.z; a0.w += a1.w;

  a0.x += __shfl_down(a0.x, 32, 64);
  a0.y += __shfl_down(a0.y, 32, 64);
  a0.z += __shfl_down(a0.z, 32, 64);
  a0.w += __shfl_down(a0.w, 32, 64);

  __shared__ float sred[4][32 * 4];
  int wid = t >> 6, lane = t & 63;
  if (lane < 32) *(float4*)&sred[wid][lane * 4] = a0;
  __syncthreads();
  if (t < 32) {
    float4 s0 = *(const float4*)&sred[0][t * 4];
    float4 s1 = *(const float4*)&sred[1][t * 4];
    float4 s2 = *(const float4*)&sred[2][t * 4];
    float4 s3 = *(const float4*)&sred[3][t * 4];
    float inv = 1.f / fmaxf((float)(end - beg), 1.f);
    float4 r;
    r.x = (s0.x + s1.x + s2.x + s3.x) * inv;
    r.y = (s0.y + s1.y + s2.y + s3.y) * inv;
    r.z = (s0.z + s1.z + s2.z + s3.z) * inv;
    r.w = (s0.w + s1.w + s2.w + s3.w) * inv;
    *(float4*)&out[(size_t)g * D + c] = r;
  }
}

__global__ void k_mlp(const float* __restrict__ cg, const float* __restrict__ pg,
                      const float* __restrict__ Wf1, const float* __restrict__ bf1,
                      const float* __restrict__ Wf2, const float* __restrict__ bf2,
                      float* __restrict__ out) {
  __shared__ float xs[256];
  __shared__ float red[128];
  int b = blockIdx.x, t = threadIdx.x;
  xs[t] = cg[b * D + t];
  xs[128 + t] = pg[b * D + t];
  __syncthreads();
  float acc = bf1[t];
  for (int k = 0; k < 256; ++k) acc = fmaf(xs[k], Wf1[k * D + t], acc);
  float hv = fmaxf(acc, 0.f);
  red[t] = hv * Wf2[t];
  for (int d = 64; d > 0; d >>= 1) {
    __syncthreads();
    if (t < d) red[t] += red[t + d];
  }
  if (t == 0) out[b] = red[0] + bf2[0];
}

// ---- launch -----------------------------------------------------------------

extern "C" void kernel_launch(void* const* d_in, const int* in_sizes, int n_in,
                              void* d_out, int out_size, void* d_ws, size_t ws_size,
                              hipStream_t stream) {
  const float* compound_feat = (const float*)d_in[0];
  const float* protein_feat  = (const float*)d_in[1];
  const int* c_src = (const int*)d_in[2];
  const int* c_dst = (const int*)d_in[3];
  const int* p_src = (const int*)d_in[4];
  const int* p_dst = (const int*)d_in[5];
  const int* c_gid = (const int*)d_in[6];
  const int* p_gid = (const int*)d_in[7];
  const float* Wc1 = (const float*)d_in[8];  const float* bc1 = (const float*)d_in[9];
  const float* Wc2 = (const float*)d_in[10]; const float* bc2 = (const float*)d_in[11];
  const float* Wp1 = (const float*)d_in[12]; const float* bp1 = (const float*)d_in[13];
  const float* Wp2 = (const float*)d_in[14]; const float* bp2 = (const float*)d_in[15];
  const float* Wf1 = (const float*)d_in[16]; const float* bf1 = (const float*)d_in[17];
  const float* Wf2 = (const float*)d_in[18]; const float* bf2 = (const float*)d_in[19];
  float* out = (float*)d_out;

  const int EC = in_sizes[2], EP = in_sizes[4];
  const int NC = in_sizes[6], NP = in_sizes[7];
  const int B  = out_size;
  const int KC = in_sizes[0] / NC;
  const int cshift = __builtin_ctz(NC / 256), cfine = NC / 256;   // 6, 64
  const int pshift = __builtin_ctz(NP / 256), pfine = NP / 256;   // 9, 512

  char* ws = (char*)d_ws;
  size_t off = 0;
  auto alloc = [&](size_t bytes) -> void* {
    void* p = ws + off;
    off += (bytes + 255) & ~(size_t)255;
    return p;
  };

  int* H       = (int*)alloc((size_t)256 * NBLK * 4);
  int* base    = (int*)alloc(((size_t)256 * NBLK + 1) * 4);
  int* baseg_c = (int*)alloc(((size_t)256 * NBLK + 1) * 4);
  int* baseg_p = (int*)alloc(((size_t)256 * NBLK + 1) * 4);
  int* spart   = (int*)alloc(64 * 4);
  int* tmpk    = (int*)alloc((size_t)EP * 4);
  int* tmpv    = (int*)alloc((size_t)EP * 4);
  int* c_outdeg = (int*)alloc((size_t)NC * 4);
  int* c_indeg  = (int*)alloc((size_t)NC * 4);
  int* p_outdeg = (int*)alloc((size_t)NP * 4);
  int* p_indeg  = (int*)alloc((size_t)NP * 4);
  float* c_ns = (float*)alloc((size_t)NC * 4);
  float* c_nd = (float*)alloc((size_t)NC * 4);
  float* p_ns = (float*)alloc((size_t)NP * 4);
  float* p_nd = (float*)alloc((size_t)NP * 4);
  int* c_rowptr = (int*)alloc((size_t)(NC + 1) * 4);
  int* p_rowptr = (int*)alloc((size_t)(NP + 1) * 4);
  int* c_col   = (int*)alloc((size_t)EC * 4);
  int* p_col   = (int*)alloc((size_t)EP * 4);
  int* cg_list = (int*)alloc((size_t)NC * 4);
  int* pg_list = (int*)alloc((size_t)NP * 4);
  __half* c_h  = (__half*)alloc((size_t)NC * D * 2);
  float*  c_m1 = (float*) alloc((size_t)NC * D * 4);
  __half* c_m2 = (__half*)alloc((size_t)NC * D * 2);
  __half* p_h  = (__half*)alloc((size_t)NP * D * 2);
  float*  p_m1 = (float*) alloc((size_t)NP * D * 4);
  __half* p_m2 = (__half*)alloc((size_t)NP * D * 2);
  float* cg = (float*)alloc((size_t)B * D * 4);
  float* pg = (float*)alloc((size_t)B * D * 4);
  (void)ws_size; (void)n_in;

  auto scan = [&](const int* in, int* outp, int n) {
    int nb = (n + SCH - 1) / SCH;
    k_scan_part<<<nb, 256, 0, stream>>>(in, spart, n);
    k_scan_top<<<1, 64, 0, stream>>>(spart, nb, outp, n);
    k_scan_down<<<nb, 256, 0, stream>>>(in, spart, outp, n);
  };
  const int HN = 256 * NBLK;

  // ---- compound preprocessing (no global atomics) ----
  k_l1hist<<<NBLK, 256, 0, stream>>>(c_src, EC, cshift, H);
  scan(H, base, HN);
  k_l1scatter1<<<NBLK, 256, 0, stream>>>(c_src, EC, cshift, base, tmpk);
  k_l2count<<<NBLK, 256, 0, stream>>>(tmpk, base, EC, cfine, c_outdeg);

  k_l1hist<<<NBLK, 256, 0, stream>>>(c_dst, EC, cshift, H);
  scan(H, base, HN);
  k_l1scatter2<<<NBLK, 256, 0, stream>>>(c_dst, c_src, EC, cshift, base, tmpk, tmpv);
  k_l2count<<<NBLK, 256, 0, stream>>>(tmpk, base, EC, cfine, c_indeg);
  scan(c_indeg, c_rowptr, NC);
  k_l2scatter<<<NBLK, 256, 0, stream>>>(tmpk, tmpv, base, EC, c_rowptr, cshift, cfine, c_col);
  k_norms<<<(NC + 255) / 256, 256, 0, stream>>>(c_outdeg, c_indeg, c_ns, c_nd, NC);

  k_l1hist<<<NBLK, 256, 0, stream>>>(c_gid, NC, 0, H);
  scan(H, baseg_c, HN);
  k_l1scatteridx<<<NBLK, 256, 0, stream>>>(c_gid, NC, 0, baseg_c, cg_list);

  // ---- protein preprocessing ----
  k_l1hist<<<NBLK, 256, 0, stream>>>(p_src, EP, pshift, H);
  scan(H, base, HN);
  k_l1scatter1<<<NBLK, 256, 0, stream>>>(p_src, EP, pshift, base, tmpk);
  k_l2count<<<NBLK, 256, 0, stream>>>(tmpk, base, EP, pfine, p_outdeg);

  k_l1hist<<<NBLK, 256, 0, stream>>>(p_dst, EP, pshift, H);
  scan(H, base, HN);
  k_l1scatter2<<<NBLK, 256, 0, stream>>>(p_dst, p_src, EP, pshift, base, tmpk, tmpv);
  k_l2count<<<NBLK, 256, 0, stream>>>(tmpk, base, EP, pfine, p_indeg);
  scan(p_indeg, p_rowptr, NP);
  k_l2scatter<<<NBLK, 256, 0, stream>>>(tmpk, tmpv, base, EP, p_rowptr, pshift, pfine, p_col);
  k_norms<<<(NP + 255) / 256, 256, 0, stream>>>(p_outdeg, p_indeg, p_ns, p_nd, NP);

  k_l1hist<<<NBLK, 256, 0, stream>>>(p_gid, NP, 0, H);
  scan(H, baseg_p, HN);
  k_l1scatteridx<<<NBLK, 256, 0, stream>>>(p_gid, NP, 0, baseg_p, pg_list);

  // ---- compound tower ----
  k_nl_gemm<<<NC / 32, 256, 0, stream>>>(compound_feat, c_ns, Wc1, c_h, KC);
  k_aggregate<false><<<NC, 128, 0, stream>>>(c_h, c_rowptr, c_col, c_nd, bc1, c_m1);
  k_nl_gemm<<<NC / 32, 256, 0, stream>>>(c_m1, c_ns, Wc2, c_h, D);
  k_aggregate<true><<<NC, 128, 0, stream>>>(c_h, c_rowptr, c_col, c_nd, bc2, c_m2);
  k_seg_mean<<<B, 256, 0, stream>>>(c_m2, baseg_c, NC, cg_list, cg);

  // ---- protein tower ----
  k_nl_gemm<<<NP / 32, 256, 0, stream>>>(protein_feat, p_ns, Wp1, p_h, D);
  k_aggregate<false><<<NP, 128, 0, stream>>>(p_h, p_rowptr, p_col, p_nd, bp1, p_m1);
  k_nl_gemm<<<NP / 32, 256, 0, stream>>>(p_m1, p_ns, Wp2, p_h, D);
  k_aggregate<true><<<NP, 128, 0, stream>>>(p_h, p_rowptr, p_col, p_nd, bp2, p_m2);
  k_seg_mean<<<B, 256, 0, stream>>>(p_m2, baseg_p, NP, pg_list, pg);

  k_mlp<<<B, D, 0, stream>>>(cg, pg, Wf1, bf1, Wf2, bf2, out);
}

// Round 6
// 751.684 us; speedup vs baseline: 2.8011x; 1.1837x over previous
//
#include <hip/hip_runtime.h>
#include <hip/hip_fp16.h>

#define D 128
#define KP 132      // padded LDS row stride for x tile
#define SCH 4096    // elements per scan block
#define NBLK 256    // blocks per level-1 distribution

// ---------------- task structs (passed by value) -----------------------------
struct HTask { const int* keys; int n; int shift; int* H; };
struct H6 { HTask t[6]; };

struct SPTask { const int* in; int n; int* part; };
struct SP6 { SPTask t[6]; };

struct SDTask { const int* in; int n; const int* part; int* out; int* total; };
struct SD6 { SDTask t[6]; };

struct ScTask { const int* k1; const int* k2; int n; int shift;
                const int* base1; const int* base2;
                int* o1; int* o2k; int* o2v; int mode; };
struct Sc4 { ScTask t[4]; };

struct CTask { const int* tmpk; const int* base; int n; int fine; int* deg; };
struct C4 { CTask t[4]; };

struct NTask { const int* outdeg; const int* indeg; float* ns; float* nd; int n; };
struct N2 { NTask t[2]; };

struct LTask { const int* tmpk; const int* tmpv; const int* base; int n;
               const int* rowptr; int shift; int fine; int* col; };
struct L2T { LTask t[2]; };

struct GTask { const float* x; const float* ns; const float* W; __half* h; int K; int nv; };
struct G2 { GTask t[2]; };

struct ATask { const __half* h; const int* rowptr; const int* col;
               const float* nd; const float* b; void* out; int n; int halfOut; };
struct A2 { ATask t[2]; };

struct MTask { const __half* x; const int* gbase; int n; const int* list; float* out; };
struct M2 { MTask t[2]; };

// ---------------- fused preprocessing ----------------------------------------

__global__ __launch_bounds__(256) void k_hist_all(H6 P) {
  HTask tk = P.t[blockIdx.y];
  __shared__ int bins[256];
  int blk = blockIdx.x, t = threadIdx.x;
  bins[t] = 0;
  __syncthreads();
  int per = (tk.n + NBLK - 1) / NBLK;
  int beg = blk * per, end = min(beg + per, tk.n);
  for (int i = beg + t; i < end; i += 256)
    atomicAdd(&bins[tk.keys[i] >> tk.shift], 1);
  __syncthreads();
  tk.H[t * NBLK + blk] = bins[t];
}

__global__ __launch_bounds__(256) void k_scan_part_all(SP6 P) {
  SPTask tk = P.t[blockIdx.y];
  int b = blockIdx.x, t = threadIdx.x;
  int base = b * SCH;
  int s = 0;
  for (int i = t; i < SCH; i += 256) {
    int idx = base + i;
    if (idx < tk.n) s += tk.in[idx];
  }
  __shared__ int red[256];
  red[t] = s;
  __syncthreads();
  for (int d = 128; d > 0; d >>= 1) {
    if (t < d) red[t] += red[t + d];
    __syncthreads();
  }
  if (t == 0) tk.part[b] = red[0];
}

// down-sweep: each block derives its global offset from the (<=32) partials
__global__ __launch_bounds__(256) void k_scan_down_all(SD6 P) {
  SDTask tk = P.t[blockIdx.y];
  int b = blockIdx.x, t = threadIdx.x;
  int lane = t & 63, wid = t >> 6;
  __shared__ int wsum[4];
  if (b == 0 && t == 0 && tk.total) {
    int s = 0;
    for (int w = 0; w < (int)gridDim.x; ++w) s += tk.part[w];
    *tk.total = s;
  }
  int offset = 0;
  for (int w = 0; w < b; ++w) offset += tk.part[w];
  int base = b * SCH;
  if (base >= tk.n) return;
  int idx0 = base + t * 16;
  int v[16];
  int s = 0;
#pragma unroll
  for (int i = 0; i < 16; ++i) {
    int idx = idx0 + i;
    v[i] = (idx < tk.n) ? tk.in[idx] : 0;
    s += v[i];
  }
  int inc = s;
  for (int d = 1; d < 64; d <<= 1) {
    int u = __shfl_up(inc, d, 64);
    if (lane >= d) inc += u;
  }
  if (lane == 63) wsum[wid] = inc;
  __syncthreads();
  int woff = 0;
  for (int w = 0; w < wid; ++w) woff += wsum[w];
  int ex = offset + woff + inc - s;
#pragma unroll
  for (int i = 0; i < 16; ++i) {
    int idx = idx0 + i;
    if (idx < tk.n) tk.out[idx] = ex;
    ex += v[i];
  }
}

// mode 0: dual edge scatter (src-only keys + (dst,src) pairs); mode 1: gid index scatter
__global__ __launch_bounds__(256) void k_scatter_all(Sc4 P) {
  ScTask tk = P.t[blockIdx.y];
  __shared__ int curA[256], curB[256];
  int blk = blockIdx.x, t = threadIdx.x;
  curA[t] = tk.base1[t * NBLK + blk];
  if (tk.mode == 0) curB[t] = tk.base2[t * NBLK + blk];
  __syncthreads();
  int per = (tk.n + NBLK - 1) / NBLK;
  int beg = blk * per, end = min(beg + per, tk.n);
  if (tk.mode == 0) {
    for (int i = beg + t; i < end; i += 256) {
      int s = tk.k1[i], d = tk.k2[i];
      int pa = atomicAdd(&curA[s >> tk.shift], 1);
      tk.o1[pa] = s;
      int pb = atomicAdd(&curB[d >> tk.shift], 1);
      tk.o2k[pb] = d;
      tk.o2v[pb] = s;
    }
  } else {
    for (int i = beg + t; i < end; i += 256) {
      int pa = atomicAdd(&curA[tk.k1[i] >> tk.shift], 1);
      tk.o1[pa] = i;
    }
  }
}

__global__ __launch_bounds__(256) void k_l2count_all(C4 P) {
  CTask tk = P.t[blockIdx.y];
  __shared__ int bins[512];
  int b = blockIdx.x, t = threadIdx.x;
  for (int f = t; f < tk.fine; f += 256) bins[f] = 0;
  __syncthreads();
  int beg = tk.base[b * NBLK];
  int end = (b == NBLK - 1) ? tk.n : tk.base[(b + 1) * NBLK];
  for (int i = beg + t; i < end; i += 256)
    atomicAdd(&bins[tk.tmpk[i] & (tk.fine - 1)], 1);
  __syncthreads();
  for (int f = t; f < tk.fine; f += 256)
    tk.deg[b * tk.fine + f] = bins[f];
}

__global__ __launch_bounds__(256) void k_norms_all(N2 P) {
  NTask tk = P.t[blockIdx.y];
  int i = blockIdx.x * blockDim.x + threadIdx.x;
  if (i < tk.n) {
    tk.ns[i] = rsqrtf(fmaxf((float)tk.outdeg[i], 1.f));
    tk.nd[i] = rsqrtf(fmaxf((float)tk.indeg[i], 1.f));
  }
}

__global__ __launch_bounds__(256) void k_l2scatter_all(L2T P) {
  LTask tk = P.t[blockIdx.y];
  __shared__ int cur[512];
  int b = blockIdx.x, t = threadIdx.x;
  int v0 = b << tk.shift;
  for (int f = t; f < tk.fine; f += 256) cur[f] = tk.rowptr[v0 + f];
  __syncthreads();
  int beg = tk.base[b * NBLK];
  int end = (b == NBLK - 1) ? tk.n : tk.base[(b + 1) * NBLK];
  for (int i = beg + t; i < end; i += 256) {
    int pos = atomicAdd(&cur[tk.tmpk[i] & (tk.fine - 1)], 1);
    tk.col[pos] = tk.tmpv[i];
  }
}

// ---------------- fused towers ------------------------------------------------

// h[v,:] = fp16( ns[v] * (x[v,:] @ W) ); 32 nodes x 128 feats per block
__global__ __launch_bounds__(256) void k_nl_gemm(G2 P) {
  GTask tk = P.t[blockIdx.y];
  int v0 = blockIdx.x * 32;
  if (v0 >= tk.nv) return;
  const int K = tk.K;
  __shared__ float xs[32][KP];
  int t = threadIdx.x;

  {
    int m = t >> 5, k = t & 31;
    for (int kk = k; kk < K; kk += 32)
      for (int mm = m; mm < 32; mm += 8)
        xs[mm][kk] = tk.x[(size_t)(v0 + mm) * K + kk];
  }
  __syncthreads();

  int tm = (t >> 5) * 4;
  int tf = (t & 31) * 4;

  float acc[4][4];
#pragma unroll
  for (int i = 0; i < 4; ++i)
#pragma unroll
    for (int j = 0; j < 4; ++j) acc[i][j] = 0.f;

  int k4max = K & ~3;
  for (int k4 = 0; k4 < k4max; k4 += 4) {
    float a[4][4], bb[4][4];
#pragma unroll
    for (int kk = 0; kk < 4; ++kk) {
      float4 w4 = *(const float4*)&tk.W[(k4 + kk) * D + tf];
      bb[kk][0] = w4.x; bb[kk][1] = w4.y; bb[kk][2] = w4.z; bb[kk][3] = w4.w;
    }
#pragma unroll
    for (int i = 0; i < 4; ++i) {
      float4 a4 = *(const float4*)&xs[tm + i][k4];
      a[i][0] = a4.x; a[i][1] = a4.y; a[i][2] = a4.z; a[i][3] = a4.w;
    }
#pragma unroll
    for (int i = 0; i < 4; ++i)
#pragma unroll
      for (int kk = 0; kk < 4; ++kk)
#pragma unroll
        for (int j = 0; j < 4; ++j)
          acc[i][j] = fmaf(a[i][kk], bb[kk][j], acc[i][j]);
  }
  for (int k = k4max; k < K; ++k) {
    float4 w4 = *(const float4*)&tk.W[k * D + tf];
    float bv[4] = {w4.x, w4.y, w4.z, w4.w};
#pragma unroll
    for (int i = 0; i < 4; ++i) {
      float av = xs[tm + i][k];
#pragma unroll
      for (int j = 0; j < 4; ++j) acc[i][j] = fmaf(av, bv[j], acc[i][j]);
    }
  }

#pragma unroll
  for (int i = 0; i < 4; ++i) {
    int v = v0 + tm + i;
    float s = tk.ns[v];
    union { __half2 h2[2]; uint2 u; } pk;
    __half2 p0, p1;
    p0.x = __float2half_rn(acc[i][0] * s); p0.y = __float2half_rn(acc[i][1] * s);
    p1.x = __float2half_rn(acc[i][2] * s); p1.y = __float2half_rn(acc[i][3] * s);
    pk.h2[0] = p0; pk.h2[1] = p1;
    *(uint2*)&tk.h[(size_t)v * D + tf] = pk.u;
  }
}

__device__ __forceinline__ void acc_half4(float4& a, const __half* p) {
  uint2 r = *(const uint2*)p;
  __half2 q0 = *(__half2*)&r.x;
  __half2 q1 = *(__half2*)&r.y;
  float2 f0 = __half22float2(q0);
  float2 f1 = __half22float2(q1);
  a.x += f0.x; a.y += f0.y; a.z += f1.x; a.w += f1.y;
}

// out[v] = relu( (sum_{dst==v} h[src]) * nd[v] + b ); 4 slots x half4, 4x unroll
__global__ __launch_bounds__(128) void k_aggregate(A2 P) {
  ATask tk = P.t[blockIdx.y];
  int v = blockIdx.x;
  if (v >= tk.n) return;
  int t = threadIdx.x;
  int slot = t >> 5;
  int c = (t & 31) * 4;
  int beg = tk.rowptr[v], end = tk.rowptr[v + 1];
  const __half* h = tk.h;
  const int* col = tk.col;

  float4 a0 = make_float4(0.f, 0.f, 0.f, 0.f);
  float4 a1 = make_float4(0.f, 0.f, 0.f, 0.f);
  float4 a2 = make_float4(0.f, 0.f, 0.f, 0.f);
  float4 a3 = make_float4(0.f, 0.f, 0.f, 0.f);
  int j = beg + slot;
  for (; j + 12 < end; j += 16) {
    int s0 = col[j], s1 = col[j + 4], s2 = col[j + 8], s3 = col[j + 12];
    acc_half4(a0, h + (size_t)s0 * D + c);
    acc_half4(a1, h + (size_t)s1 * D + c);
    acc_half4(a2, h + (size_t)s2 * D + c);
    acc_half4(a3, h + (size_t)s3 * D + c);
  }
  for (; j < end; j += 4)
    acc_half4(a0, h + (size_t)col[j] * D + c);
  a0.x += a1.x + a2.x + a3.x;
  a0.y += a1.y + a2.y + a3.y;
  a0.z += a1.z + a2.z + a3.z;
  a0.w += a1.w + a2.w + a3.w;

  a0.x += __shfl_down(a0.x, 32, 64);
  a0.y += __shfl_down(a0.y, 32, 64);
  a0.z += __shfl_down(a0.z, 32, 64);
  a0.w += __shfl_down(a0.w, 32, 64);

  __shared__ float sred[32 * 4];
  if (t >= 64 && t < 96) *(float4*)&sred[(t - 64) * 4] = a0;
  __syncthreads();
  if (t < 32) {
    float4 o = *(const float4*)&sred[t * 4];
    a0.x += o.x; a0.y += o.y; a0.z += o.z; a0.w += o.w;
    float s = tk.nd[v];
    float4 r;
    r.x = fmaxf(fmaf(a0.x, s, tk.b[c + 0]), 0.f);
    r.y = fmaxf(fmaf(a0.y, s, tk.b[c + 1]), 0.f);
    r.z = fmaxf(fmaf(a0.z, s, tk.b[c + 2]), 0.f);
    r.w = fmaxf(fmaf(a0.w, s, tk.b[c + 3]), 0.f);
    if (tk.halfOut) {
      union { __half2 h2[2]; uint2 u; } pk;
      __half2 p0, p1;
      p0.x = __float2half_rn(r.x); p0.y = __float2half_rn(r.y);
      p1.x = __float2half_rn(r.z); p1.y = __float2half_rn(r.w);
      pk.h2[0] = p0; pk.h2[1] = p1;
      *(uint2*)&((__half*)tk.out)[(size_t)v * D + c] = pk.u;
    } else {
      *(float4*)&((float*)tk.out)[(size_t)v * D + c] = r;
    }
  }
}

__global__ __launch_bounds__(256) void k_seg_mean(M2 P) {
  MTask tk = P.t[blockIdx.y];
  int g = blockIdx.x, t = threadIdx.x;
  int slot = t >> 5;
  int c = (t & 31) * 4;
  int beg = tk.gbase[g * NBLK];
  int end = (g == (int)gridDim.x - 1) ? tk.n : tk.gbase[(g + 1) * NBLK];
  const __half* x = tk.x;
  const int* list = tk.list;

  float4 a0 = make_float4(0.f, 0.f, 0.f, 0.f);
  float4 a1 = make_float4(0.f, 0.f, 0.f, 0.f);
  int j = beg + slot;
  for (; j + 8 < end; j += 16) {
    int s0 = list[j], s1 = list[j + 8];
    acc_half4(a0, x + (size_t)s0 * D + c);
    acc_half4(a1, x + (size_t)s1 * D + c);
  }
  if (j < end)
    acc_half4(a0, x + (size_t)list[j] * D + c);
  a0.x += a1.x; a0.y += a1.y; a0.z += a1.z; a0.w += a1.w;

  a0.x += __shfl_down(a0.x, 32, 64);
  a0.y += __shfl_down(a0.y, 32, 64);
  a0.z += __shfl_down(a0.z, 32, 64);
  a0.w += __shfl_down(a0.w, 32, 64);

  __shared__ float sred[4][32 * 4];
  int wid = t >> 6, lane = t & 63;
  if (lane < 32) *(float4*)&sred[wid][lane * 4] = a0;
  __syncthreads();
  if (t < 32) {
    float4 s0 = *(const float4*)&sred[0][t * 4];
    float4 s1 = *(const float4*)&sred[1][t * 4];
    float4 s2 = *(const float4*)&sred[2][t * 4];
    float4 s3 = *(const float4*)&sred[3][t * 4];
    float inv = 1.f / fmaxf((float)(end - beg), 1.f);
    float4 r;
    r.x = (s0.x + s1.x + s2.x + s3.x) * inv;
    r.y = (s0.y + s1.y + s2.y + s3.y) * inv;
    r.z = (s0.z + s1.z + s2.z + s3.z) * inv;
    r.w = (s0.w + s1.w + s2.w + s3.w) * inv;
    *(float4*)&tk.out[(size_t)g * D + c] = r;
  }
}

__global__ void k_mlp(const float* __restrict__ cg, const float* __restrict__ pg,
                      const float* __restrict__ Wf1, const float* __restrict__ bf1,
                      const float* __restrict__ Wf2, const float* __restrict__ bf2,
                      float* __restrict__ out) {
  __shared__ float xs[256];
  __shared__ float red[128];
  int b = blockIdx.x, t = threadIdx.x;
  xs[t] = cg[b * D + t];
  xs[128 + t] = pg[b * D + t];
  __syncthreads();
  float acc = bf1[t];
  for (int k = 0; k < 256; ++k) acc = fmaf(xs[k], Wf1[k * D + t], acc);
  float hv = fmaxf(acc, 0.f);
  red[t] = hv * Wf2[t];
  for (int d = 64; d > 0; d >>= 1) {
    __syncthreads();
    if (t < d) red[t] += red[t + d];
  }
  if (t == 0) out[b] = red[0] + bf2[0];
}

// ---------------- launch ------------------------------------------------------

extern "C" void kernel_launch(void* const* d_in, const int* in_sizes, int n_in,
                              void* d_out, int out_size, void* d_ws, size_t ws_size,
                              hipStream_t stream) {
  const float* compound_feat = (const float*)d_in[0];
  const float* protein_feat  = (const float*)d_in[1];
  const int* c_src = (const int*)d_in[2];
  const int* c_dst = (const int*)d_in[3];
  const int* p_src = (const int*)d_in[4];
  const int* p_dst = (const int*)d_in[5];
  const int* c_gid = (const int*)d_in[6];
  const int* p_gid = (const int*)d_in[7];
  const float* Wc1 = (const float*)d_in[8];  const float* bc1 = (const float*)d_in[9];
  const float* Wc2 = (const float*)d_in[10]; const float* bc2 = (const float*)d_in[11];
  const float* Wp1 = (const float*)d_in[12]; const float* bp1 = (const float*)d_in[13];
  const float* Wp2 = (const float*)d_in[14]; const float* bp2 = (const float*)d_in[15];
  const float* Wf1 = (const float*)d_in[16]; const float* bf1 = (const float*)d_in[17];
  const float* Wf2 = (const float*)d_in[18]; const float* bf2 = (const float*)d_in[19];
  float* out = (float*)d_out;

  const int EC = in_sizes[2], EP = in_sizes[4];
  const int NC = in_sizes[6], NP = in_sizes[7];
  const int B  = out_size;
  const int KC = in_sizes[0] / NC;
  const int cshift = __builtin_ctz(NC / 256), cfine = NC / 256;   // 6, 64
  const int pshift = __builtin_ctz(NP / 256), pfine = NP / 256;   // 9, 512
  const int HN = 256 * NBLK;                                      // 65536

  char* ws = (char*)d_ws;
  size_t off = 0;
  auto alloc = [&](size_t bytes) -> void* {
    void* p = ws + off;
    off += (bytes + 255) & ~(size_t)255;
    return p;
  };

  int* H0 = (int*)alloc((size_t)HN * 4);   // c_src dist -> base after scan
  int* H1 = (int*)alloc((size_t)HN * 4);   // c_dst dist
  int* H2 = (int*)alloc((size_t)HN * 4);   // c_gid dist
  int* H3 = (int*)alloc((size_t)HN * 4);   // p_src dist
  int* H4 = (int*)alloc((size_t)HN * 4);   // p_dst dist
  int* H5 = (int*)alloc((size_t)HN * 4);   // p_gid dist
  int* partH = (int*)alloc((size_t)6 * 32 * 4);
  int* partD = (int*)alloc((size_t)2 * 32 * 4);
  int* tmps_c = (int*)alloc((size_t)EC * 4);
  int* tmpd_c = (int*)alloc((size_t)EC * 4);
  int* tmpv_c = (int*)alloc((size_t)EC * 4);
  int* tmps_p = (int*)alloc((size_t)EP * 4);
  int* tmpd_p = (int*)alloc((size_t)EP * 4);
  int* tmpv_p = (int*)alloc((size_t)EP * 4);
  int* c_outdeg = (int*)alloc((size_t)NC * 4);
  int* c_indeg  = (int*)alloc((size_t)NC * 4);
  int* p_outdeg = (int*)alloc((size_t)NP * 4);
  int* p_indeg  = (int*)alloc((size_t)NP * 4);
  float* c_ns = (float*)alloc((size_t)NC * 4);
  float* c_nd = (float*)alloc((size_t)NC * 4);
  float* p_ns = (float*)alloc((size_t)NP * 4);
  float* p_nd = (float*)alloc((size_t)NP * 4);
  int* c_rowptr = (int*)alloc((size_t)(NC + 1) * 4);
  int* p_rowptr = (int*)alloc((size_t)(NP + 1) * 4);
  int* c_col   = (int*)alloc((size_t)EC * 4);
  int* p_col   = (int*)alloc((size_t)EP * 4);
  int* cg_list = (int*)alloc((size_t)NC * 4);
  int* pg_list = (int*)alloc((size_t)NP * 4);
  __half* c_h  = (__half*)alloc((size_t)NC * D * 2);
  float*  c_m1 = (float*) alloc((size_t)NC * D * 4);
  __half* c_m2 = (__half*)alloc((size_t)NC * D * 2);
  __half* p_h  = (__half*)alloc((size_t)NP * D * 2);
  float*  p_m1 = (float*) alloc((size_t)NP * D * 4);
  __half* p_m2 = (__half*)alloc((size_t)NP * D * 2);
  float* cg = (float*)alloc((size_t)B * D * 4);
  float* pg = (float*)alloc((size_t)B * D * 4);
  (void)ws_size; (void)n_in;

  // 1) all six 256-bin histograms
  {
    H6 P = {{{c_src, EC, cshift, H0}, {c_dst, EC, cshift, H1}, {c_gid, NC, 0, H2},
             {p_src, EP, pshift, H3}, {p_dst, EP, pshift, H4}, {p_gid, NP, 0, H5}}};
    k_hist_all<<<dim3(NBLK, 6), 256, 0, stream>>>(P);
  }
  // 2) scan the six H arrays in place (HN=65536 -> 16 scan blocks each)
  {
    SP6 Pp = {{{H0, HN, partH + 0}, {H1, HN, partH + 32}, {H2, HN, partH + 64},
               {H3, HN, partH + 96}, {H4, HN, partH + 128}, {H5, HN, partH + 160}}};
    k_scan_part_all<<<dim3(16, 6), 256, 0, stream>>>(Pp);
    SD6 Pd = {{{H0, HN, partH + 0, H0, nullptr}, {H1, HN, partH + 32, H1, nullptr},
               {H2, HN, partH + 64, H2, nullptr}, {H3, HN, partH + 96, H3, nullptr},
               {H4, HN, partH + 128, H4, nullptr}, {H5, HN, partH + 160, H5, nullptr}}};
    k_scan_down_all<<<dim3(16, 6), 256, 0, stream>>>(Pd);
  }
  // 3) all level-1 scatters (c edges, p edges, c gid, p gid)
  {
    Sc4 P = {{{c_src, c_dst, EC, cshift, H0, H1, tmps_c, tmpd_c, tmpv_c, 0},
              {p_src, p_dst, EP, pshift, H3, H4, tmps_p, tmpd_p, tmpv_p, 0},
              {c_gid, nullptr, NC, 0, H2, nullptr, cg_list, nullptr, nullptr, 1},
              {p_gid, nullptr, NP, 0, H5, nullptr, pg_list, nullptr, nullptr, 1}}};
    k_scatter_all<<<dim3(NBLK, 4), 256, 0, stream>>>(P);
  }
  // 4) level-2 counts -> out/in degrees
  {
    C4 P = {{{tmps_c, H0, EC, cfine, c_outdeg}, {tmpd_c, H1, EC, cfine, c_indeg},
             {tmps_p, H3, EP, pfine, p_outdeg}, {tmpd_p, H4, EP, pfine, p_indeg}}};
    k_l2count_all<<<dim3(NBLK, 4), 256, 0, stream>>>(P);
  }
  // 5) scan indegrees -> rowptr (with totals)
  {
    SP6 Pp; Pp.t[0] = {c_indeg, NC, partD + 0}; Pp.t[1] = {p_indeg, NP, partD + 32};
    Pp.t[2] = Pp.t[3] = Pp.t[4] = Pp.t[5] = SPTask{c_indeg, 0, partD + 0};
    k_scan_part_all<<<dim3(32, 2), 256, 0, stream>>>(Pp);
    SD6 Pd; Pd.t[0] = {c_indeg, NC, partD + 0, c_rowptr, c_rowptr + NC};
    Pd.t[1] = {p_indeg, NP, partD + 32, p_rowptr, p_rowptr + NP};
    Pd.t[2] = Pd.t[3] = Pd.t[4] = Pd.t[5] = Pd.t[0];
    k_scan_down_all<<<dim3(32, 2), 256, 0, stream>>>(Pd);
  }
  // 6) norms
  {
    N2 P = {{{c_outdeg, c_indeg, c_ns, c_nd, NC}, {p_outdeg, p_indeg, p_ns, p_nd, NP}}};
    k_norms_all<<<dim3((NP + 255) / 256, 2), 256, 0, stream>>>(P);
  }
  // 7) level-2 scatter -> CSR col
  {
    L2T P = {{{tmpd_c, tmpv_c, H1, EC, c_rowptr, cshift, cfine, c_col},
              {tmpd_p, tmpv_p, H4, EP, p_rowptr, pshift, pfine, p_col}}};
    k_l2scatter_all<<<dim3(NBLK, 2), 256, 0, stream>>>(P);
  }

  // ---- towers (c and p fused per stage) ----
  const int gmax = NP / 32;     // 4096 >= NC/32
  {
    G2 P = {{{compound_feat, c_ns, Wc1, c_h, KC, NC}, {protein_feat, p_ns, Wp1, p_h, D, NP}}};
    k_nl_gemm<<<dim3(gmax, 2), 256, 0, stream>>>(P);
  }
  {
    A2 P = {{{c_h, c_rowptr, c_col, c_nd, bc1, c_m1, NC, 0},
             {p_h, p_rowptr, p_col, p_nd, bp1, p_m1, NP, 0}}};
    k_aggregate<<<dim3(NP, 2), 128, 0, stream>>>(P);
  }
  {
    G2 P = {{{c_m1, c_ns, Wc2, c_h, D, NC}, {p_m1, p_ns, Wp2, p_h, D, NP}}};
    k_nl_gemm<<<dim3(gmax, 2), 256, 0, stream>>>(P);
  }
  {
    A2 P = {{{c_h, c_rowptr, c_col, c_nd, bc2, c_m2, NC, 1},
             {p_h, p_rowptr, p_col, p_nd, bp2, p_m2, NP, 1}}};
    k_aggregate<<<dim3(NP, 2), 128, 0, stream>>>(P);
  }
  {
    M2 P = {{{c_m2, H2, NC, cg_list, cg}, {p_m2, H5, NP, pg_list, pg}}};
    k_seg_mean<<<dim3(B, 2), 256, 0, stream>>>(P);
  }

  k_mlp<<<B, D, 0, stream>>>(cg, pg, Wf1, bf1, Wf2, bf2, out);
}